// Round 12
// baseline (167.254 us; speedup 1.0000x reference)
//
#include <hip/hip_runtime.h>
#include <math.h>

typedef unsigned short u16;
typedef __attribute__((ext_vector_type(8))) short frag_ab;  // 8 bf16
typedef __attribute__((ext_vector_type(4))) float frag_cd;  // 4 fp32

#define BATCH 8
#define NN 128
#define FS 128
#define FV 64
#define NB 8
#define HID 64
#define ROUT 320
#define HSTRB 72    // hid bf16 LDS row stride (shorts), layer-1 kernel
#define HSTRF 68    // hid fp32 LDS row stride (floats), layer-0 kernel

// ---- ws layout (float offsets); s:[b][f][n], V:[b][f*3+c3][n], t:[b][g][n] ----
#define SZ_S (BATCH*FS*NN)
#define SZ_V (BATCH*FV*3*NN)
#define SZ_T (BATCH*FV*NN)
#define N_W2B (ROUT*HID)            // ushort count (layer-1 Wr2 in bf16)
#define OFF_SB 0
#define OFF_VB (OFF_SB+SZ_S)
#define OFF_T1 (OFF_VB+SZ_V)
#define OFF_W2B (OFF_T1+SZ_T)       // N_W2B ushorts = 10240 floats
#define OFF_RBE (OFF_W2B+N_W2B/2)   // [bk][n(8)][i(128)] fp32 = 1,048,576 floats
#define OFF_VHE (OFF_RBE+BATCH*NN*NB*NN)  // [bk][c3(3)][i(128)] fp32 = 393,216 floats

__device__ __forceinline__ float silu_f(float x){ return x * (1.0f/(1.0f + __expf(-x))); }

__device__ __forceinline__ u16 f2bf(float x){
  union { float f; unsigned int u; } v; v.f = x;
  unsigned int r = v.u + 0x7fffu + ((v.u >> 16) & 1u);
  return (u16)(r >> 16);
}

// ---------------- Layer 0 (specialized: s=species uniform, V=0, t uniform) ----------------
// One block per (b,k); 320 threads. Also stores rbE/vhatE (layer-independent edge basis)
// for layer 1, and converts a 20-elem slice of Wr2[layer1] -> bf16 w2b.
__global__ __launch_bounds__(320) void layer0_kernel(
    const float* __restrict__ pos,
    const float* __restrict__ species,  // (128)
    const float* __restrict__ Wr1l,     // (8,64) layer0
    const float* __restrict__ Wr2,      // (2,64,320) fp32 (both layers)
    const float* __restrict__ Wsv,      // (2,128,64)
    const float* __restrict__ WmixSl,   // (192,128) layer0
    const float* __restrict__ WmixVl,   // (128,64) layer0
    float* __restrict__ sOut,           // [b][f][n]
    float* __restrict__ vOut,           // [b][f*3+c3][n]
    float* __restrict__ tOut,           // [b][g][n]
    u16*   __restrict__ w2b,            // (320,64) bf16 c-major, layer1
    float* __restrict__ rbE,            // [bk][8][128]
    float* __restrict__ vhatE)          // [bk][3][128]
{
  const int tid = threadIdx.x;
  const int b   = blockIdx.x >> 7;
  const int k   = blockIdx.x & 127;

  __shared__ float hidF[128*HSTRF];    // 34.8 KB
  __shared__ float vhx[128], vhy[128], vhz[128];
  __shared__ float colsum[4][64];
  __shared__ float aggS[128];
  __shared__ float aggV1[192];
  __shared__ float sNew[FS];
  __shared__ float t0L[64];

  const float* pb   = pos + b*NN*3;
  const float* Wr2l = Wr2;            // layer0 fp32 (64,320)

  // ---- phase 0: tid<256: i=t&127, half=t>>7 computes half a hid row (fp32) ----
  if (tid < 256){
    const int i    = tid & 127;
    const int half = tid >> 7;
    float vx = pb[k*3+0]-pb[i*3+0];
    float vy = pb[k*3+1]-pb[i*3+1];
    float vz = pb[k*3+2]-pb[i*3+2];
    float r = sqrtf(vx*vx+vy*vy+vz*vz) + 1e-8f;
    float inv = 1.0f/r;
    float hx = vx*inv, hy = vy*inv, hz = vz*inv;
    if (half==0){ vhx[i]=hx; vhy[i]=hy; vhz[i]=hz; }
    float u = r*0.2f;
    float env = 0.0f;
    if (u < 1.0f && i != k){
      float u2=u*u, u6=u2*u2*u2;
      env = 1.0f - 28.0f*u6 + 48.0f*u6*u - 21.0f*u6*u2;
    }
    float coef = 0.6324555320336759f * inv * env;
    float th   = r * 0.6283185307179586f;     // pi*r/5
    // sin(n*th) recurrence: 2 transcendentals instead of 8
    float s1 = __sinf(th), c1 = __cosf(th);
    float rb[NB];
    rb[0] = coef*s1;
    float twoc = 2.f*c1, sp = s1, spp = 0.f;
    #pragma unroll
    for(int n=1;n<NB;n++){ float s = twoc*sp - spp; spp = sp; sp = s; rb[n] = coef*s; }
    if (half==0){
      float* rp = rbE + (size_t)blockIdx.x*(NB*NN);
      #pragma unroll
      for(int n=0;n<NB;n++) rp[n*NN+i] = rb[n];
      float* vp = vhatE + (size_t)blockIdx.x*(3*NN);
      vp[i]=hx; vp[NN+i]=hy; vp[2*NN+i]=hz;
    }
    #pragma unroll
    for(int jg=0;jg<8;jg++){
      const int jgg = half*8 + jg;
      float h0=0.f,h1=0.f,h2=0.f,h3=0.f;
      #pragma unroll
      for(int n=0;n<NB;n++){
        const float* wr = Wr1l + n*HID + jgg*4;
        float rn = rb[n];
        h0 = fmaf(rn, wr[0], h0);
        h1 = fmaf(rn, wr[1], h1);
        h2 = fmaf(rn, wr[2], h2);
        h3 = fmaf(rn, wr[3], h3);
      }
      float4 hh = make_float4(silu_f(h0), silu_f(h1), silu_f(h2), silu_f(h3));
      *(float4*)&hidF[i*HSTRF + jgg*4] = hh;
    }
  } else {
    // t0L[g] = species @ Wsv0  (uniform over nodes)
    const int g = tid - 256;   // 0..63
    float a0=0.f, a1=0.f;
    #pragma unroll 8
    for (int c=0; c<FS; c+=2){
      a0 = fmaf(species[c],   Wsv[c*FV+g],     a0);
      a1 = fmaf(species[c+1], Wsv[(c+1)*FV+g], a1);
    }
    t0L[g] = a0+a1;
  }
  __syncthreads();

  // ---- phase A: weighted column sums over i (tid<256: j=t&63, var=t>>6) ----
  if (tid < 256){
    const int j   = tid & 63;
    const int var = tid >> 6;
    float a0 = 0.f, a1 = 0.f;
    if (var == 0){
      #pragma unroll 8
      for (int i=0;i<128;i+=2){ a0 += hidF[i*HSTRF + j]; a1 += hidF[(i+1)*HSTRF + j]; }
    } else {
      const float* wv = (var==1) ? vhx : (var==2) ? vhy : vhz;
      #pragma unroll 8
      for (int i=0;i<128;i+=2){
        a0 = fmaf(hidF[i*HSTRF + j],     wv[i],   a0);
        a1 = fmaf(hidF[(i+1)*HSTRF + j], wv[i+1], a1);
      }
    }
    colsum[var][j] = a0+a1;
  } else if (tid < 276){
    // convert this block's 20-element slice of Wr2[layer1] to bf16 (for layer1)
    const int t = blockIdx.x*20 + (tid-256);   // 1024*20 = 20480 = N_W2B
    const int j = t & 63, c = t >> 6;
    w2b[t] = f2bf(Wr2[HID*ROUT + j*ROUT + c]);
  }
  __syncthreads();

  // ---- phase B: project colsums through W2 columns ----
  if (tid < 128){
    const int c = tid;
    float d0 = 0.f, d1 = 0.f;
    #pragma unroll 8
    for (int j=0;j<HID;j+=2){
      d0 = fmaf(colsum[0][j],   Wr2l[j*ROUT + c],     d0);
      d1 = fmaf(colsum[0][j+1], Wr2l[(j+1)*ROUT + c], d1);
    }
    aggS[c] = species[c] * (d0+d1) * (1.0f/128.0f);
  } else {
    const int idx = tid - 128;          // 0..191
    const int f = idx & 63, c3 = idx >> 6;
    float d0 = 0.f, d1 = 0.f;
    #pragma unroll 8
    for (int j=0;j<HID;j+=2){
      d0 = fmaf(colsum[1+c3][j],   Wr2l[j*ROUT + 192 + f],     d0);
      d1 = fmaf(colsum[1+c3][j+1], Wr2l[(j+1)*ROUT + 192 + f], d1);
    }
    aggV1[f*3+c3] = t0L[f] * (d0+d1) * (1.0f/128.0f);
  }
  __syncthreads();

  // ---- E1: s update (tid<128) | V update (tid 128..319) — disjoint ranges ----
  if (tid < FS){
    float a0=0.f, a1=0.f, a2=0.f, a3=0.f;
    #pragma unroll 8
    for (int cc=0; cc<128; cc+=4){
      a0 = fmaf(aggS[cc],   WmixSl[cc*FS+tid],     a0);
      a1 = fmaf(aggS[cc+1], WmixSl[(cc+1)*FS+tid], a1);
      a2 = fmaf(aggS[cc+2], WmixSl[(cc+2)*FS+tid], a2);
      a3 = fmaf(aggS[cc+3], WmixSl[(cc+3)*FS+tid], a3);
    }
    float sn = species[tid] + silu_f((a0+a1)+(a2+a3));
    sNew[tid] = sn;
    sOut[(b*FS+tid)*NN + k] = sn;
  } else {
    const int o = tid - 128;            // 0..191
    const int g = o/3, c3 = o - g*3;
    float a0=0.f, a1=0.f;
    #pragma unroll 8
    for (int f=0; f<FV; f+=2){
      a0 = fmaf(aggV1[f*3+c3],     WmixVl[f*FV+g],     a0);
      a1 = fmaf(aggV1[(f+1)*3+c3], WmixVl[(f+1)*FV+g], a1);
    }
    vOut[(b*FV*3 + o)*NN + k] = a0 + a1;
  }
  __syncthreads();
  // ---- E2: t for layer 1 (from updated s) ----
  if (tid < FV){
    const float* Wsv1 = Wsv + FS*FV;
    float a0=0.f, a1=0.f, a2=0.f, a3=0.f;
    #pragma unroll 8
    for (int f=0; f<FS; f+=4){
      a0 = fmaf(sNew[f],   Wsv1[f*FV+tid],     a0);
      a1 = fmaf(sNew[f+1], Wsv1[(f+1)*FV+tid], a1);
      a2 = fmaf(sNew[f+2], Wsv1[(f+2)*FV+tid], a2);
      a3 = fmaf(sNew[f+3], Wsv1[(f+3)*FV+tid], a3);
    }
    tOut[(b*FV+tid)*NN + k] = (a0+a1)+(a2+a3);
  }
}

// ---------------- Layer 1 (final): one block per (b,k); 512 threads = 8 waves ----------------
// wave w: wq=w&3 channel group, sh=w>>2 sender half. Main loop = 5 compile-time sections.
// phase0 loads rb/vhat from layer0 (no geometry/sin) and uses all 512 threads.
__global__ __launch_bounds__(512) void layer_kernel(
    const float* __restrict__ pos,
    const float* __restrict__ sIn,    // [b][f][n]
    const float* __restrict__ vIn,    // [b][f*3+c3][n]
    const float* __restrict__ tIn,    // [b][g][n]
    const float* __restrict__ rbE,    // [bk][8][128]
    const float* __restrict__ vhatE,  // [bk][3][128]
    const float* __restrict__ Wr1l,   // (8,64) layer1
    const u16*   __restrict__ w2bl,   // (320,64) bf16, c-major
    const float* __restrict__ WmixSl, // (192,128)
    const float* __restrict__ WmixVl, // (128,64)
    const float* __restrict__ WoutS,
    const float* __restrict__ WoutV,
    float* __restrict__ outp)
{
  const int tid  = threadIdx.x;
  const int b    = blockIdx.x >> 7;
  const int k    = blockIdx.x & 127;
  const int w    = tid >> 6;
  const int lane = tid & 63;
  const int col  = lane & 15;
  const int quad = lane >> 4;
  const int wq   = w & 3;       // channel group
  const int sh   = w >> 2;      // sender half

  __shared__ u16   hidB[128*HSTRB];           // 18.4 KB
  __shared__ float vhx[128], vhy[128], vhz[128];
  __shared__ float aggP[2][576];
  __shared__ float aggC[576];
  __shared__ float sPart[2][FS];
  __shared__ float sNew[FS];
  __shared__ float vNewL[192];
  __shared__ float comL[3];

  const float* pb = pos + b*NN*3;

  // ---- phase 0 (all 512 threads): i=t&127, q=t>>7 computes quarter hid row ----
  {
    const int i = tid & 127;
    const int q = tid >> 7;
    const float* rp = rbE + (size_t)blockIdx.x*(NB*NN);
    float rb[NB];
    #pragma unroll
    for(int n=0;n<NB;n++) rb[n] = rp[n*NN + i];
    if (q==0){
      const float* vp = vhatE + (size_t)blockIdx.x*(3*NN);
      vhx[i]=vp[i]; vhy[i]=vp[NN+i]; vhz[i]=vp[2*NN+i];
    }
    u16* hrow = hidB + i*HSTRB;
    #pragma unroll
    for(int jg=0;jg<4;jg++){
      const int j0 = q*16 + jg*4;
      float h0=0.f,h1=0.f,h2=0.f,h3=0.f;
      #pragma unroll
      for(int n=0;n<NB;n++){
        const float* wr = Wr1l + n*HID + j0;
        float rn = rb[n];
        h0 = fmaf(rn, wr[0], h0);
        h1 = fmaf(rn, wr[1], h1);
        h2 = fmaf(rn, wr[2], h2);
        h3 = fmaf(rn, wr[3], h3);
      }
      ushort4 uu = make_ushort4(f2bf(silu_f(h0)), f2bf(silu_f(h1)),
                                f2bf(silu_f(h2)), f2bf(silu_f(h3)));
      *(ushort4*)(hrow + j0) = uu;
    }
    if (tid >= 509){
      const int c3 = tid - 509;
      float a0=0.f, a1=0.f;
      for (int n=0;n<NN;n+=2){ a0 += pb[n*3+c3]; a1 += pb[(n+1)*3+c3]; }
      comL[c3] = (a0+a1) * (1.0f/128.0f);
    }
  }
  __syncthreads();

  const float* sIb = sIn + b*FS*NN;
  const float* vIb = vIn + b*FV*3*NN;
  const float* tIb = tIn + b*FV*NN;
  const int i00 = sh*64 + quad*4;

#define MFMA_PAIR(accv, MT) \
    { const int hrow_ = (sh*64 + (MT)*16 + col)*HSTRB + quad*8; \
      frag_ab a0_ = *(const frag_ab*)&hidB[hrow_]; \
      frag_ab a1_ = *(const frag_ab*)&hidB[hrow_ + 32]; \
      accv = __builtin_amdgcn_mfma_f32_16x16x32_bf16(a0_, b0, accv, 0,0,0); \
      accv = __builtin_amdgcn_mfma_f32_16x16x32_bf16(a1_, b1, accv, 0,0,0); }

  // q = 0,1 : m0a
  #pragma unroll
  for (int q=0; q<2; q++){
    const int ntg = q*4 + wq;
    const int c   = ntg*16 + col;
    const u16* wp = w2bl + c*HID + quad*8;
    const frag_ab b0 = *(const frag_ab*)(wp);
    const frag_ab b1 = *(const frag_ab*)(wp + 32);
    const float* fb = sIb + c*NN + i00;
    float sA = 0.f;
    #pragma unroll
    for (int mt=0; mt<4; mt++){
      frag_cd acc = {0.f,0.f,0.f,0.f};
      MFMA_PAIR(acc, mt);
      float4 s4 = *(const float4*)&fb[mt*16];
      sA += acc[0]*s4.x + acc[1]*s4.y + acc[2]*s4.z + acc[3]*s4.w;
    }
    sA += __shfl_xor(sA, 16, 64);
    sA += __shfl_xor(sA, 32, 64);
    if (lane < 16) aggP[sh][ntg*16 + lane] = sA;
  }
  // q = 2 : m0b
  {
    const int ntg = 8 + wq;
    const int c   = ntg*16 + col;
    const u16* wp = w2bl + c*HID + quad*8;
    const frag_ab b0 = *(const frag_ab*)(wp);
    const frag_ab b1 = *(const frag_ab*)(wp + 32);
    const int f = c - FS;
    const float* fb = vIb + f*3*NN + i00;
    float sA = 0.f;
    #pragma unroll
    for (int mt=0; mt<4; mt++){
      frag_cd acc = {0.f,0.f,0.f,0.f};
      MFMA_PAIR(acc, mt);
      float4 vx4 = *(const float4*)&fb[mt*16];
      float4 vy4 = *(const float4*)&fb[NN + mt*16];
      float4 vz4 = *(const float4*)&fb[2*NN + mt*16];
      float4 hx4 = *(const float4*)&vhx[i00 + mt*16];
      float4 hy4 = *(const float4*)&vhy[i00 + mt*16];
      float4 hz4 = *(const float4*)&vhz[i00 + mt*16];
      float d0 = vx4.x*hx4.x + vy4.x*hy4.x + vz4.x*hz4.x;
      float d1 = vx4.y*hx4.y + vy4.y*hy4.y + vz4.y*hz4.y;
      float d2 = vx4.z*hx4.z + vy4.z*hy4.z + vz4.z*hz4.z;
      float d3 = vx4.w*hx4.w + vy4.w*hy4.w + vz4.w*hz4.w;
      sA += acc[0]*d0 + acc[1]*d1 + acc[2]*d2 + acc[3]*d3;
    }
    sA += __shfl_xor(sA, 16, 64);
    sA += __shfl_xor(sA, 32, 64);
    if (lane < 16) aggP[sh][ntg*16 + lane] = sA;
  }
  // q = 3 : m1a
  {
    const int ntg = 12 + wq;
    const int c   = ntg*16 + col;
    const u16* wp = w2bl + c*HID + quad*8;
    const frag_ab b0 = *(const frag_ab*)(wp);
    const frag_ab b1 = *(const frag_ab*)(wp + 32);
    const int f = c - (FS+FV);
    const float* fb = tIb + f*NN + i00;
    float sX=0.f, sY=0.f, sZ=0.f;
    #pragma unroll
    for (int mt=0; mt<4; mt++){
      frag_cd acc = {0.f,0.f,0.f,0.f};
      MFMA_PAIR(acc, mt);
      float4 t4 = *(const float4*)&fb[mt*16];
      float4 hx4 = *(const float4*)&vhx[i00 + mt*16];
      float4 hy4 = *(const float4*)&vhy[i00 + mt*16];
      float4 hz4 = *(const float4*)&vhz[i00 + mt*16];
      float t0_ = acc[0]*t4.x, t1_ = acc[1]*t4.y, t2_ = acc[2]*t4.z, t3_ = acc[3]*t4.w;
      sX += t0_*hx4.x + t1_*hx4.y + t2_*hx4.z + t3_*hx4.w;
      sY += t0_*hy4.x + t1_*hy4.y + t2_*hy4.z + t3_*hy4.w;
      sZ += t0_*hz4.x + t1_*hz4.y + t2_*hz4.z + t3_*hz4.w;
    }
    sX += __shfl_xor(sX,16,64); sX += __shfl_xor(sX,32,64);
    sY += __shfl_xor(sY,16,64); sY += __shfl_xor(sY,32,64);
    sZ += __shfl_xor(sZ,16,64); sZ += __shfl_xor(sZ,32,64);
    if (lane < 16){
      const int f2 = (ntg*16 + lane) - 192;
      aggP[sh][192 + f2*3+0]=sX; aggP[sh][192 + f2*3+1]=sY; aggP[sh][192 + f2*3+2]=sZ;
    }
  }
  // q = 4 : m1b
  {
    const int ntg = 16 + wq;
    const int c   = ntg*16 + col;
    const u16* wp = w2bl + c*HID + quad*8;
    const frag_ab b0 = *(const frag_ab*)(wp);
    const frag_ab b1 = *(const frag_ab*)(wp + 32);
    const int f = c - (FS+2*FV);
    const float* fb = vIb + f*3*NN + i00;
    float sX=0.f, sY=0.f, sZ=0.f;
    #pragma unroll
    for (int mt=0; mt<4; mt++){
      frag_cd acc = {0.f,0.f,0.f,0.f};
      MFMA_PAIR(acc, mt);
      float4 vx4 = *(const float4*)&fb[mt*16];
      float4 vy4 = *(const float4*)&fb[NN + mt*16];
      float4 vz4 = *(const float4*)&fb[2*NN + mt*16];
      sX += acc[0]*vx4.x + acc[1]*vx4.y + acc[2]*vx4.z + acc[3]*vx4.w;
      sY += acc[0]*vy4.x + acc[1]*vy4.y + acc[2]*vy4.z + acc[3]*vy4.w;
      sZ += acc[0]*vz4.x + acc[1]*vz4.y + acc[2]*vz4.z + acc[3]*vz4.w;
    }
    sX += __shfl_xor(sX,16,64); sX += __shfl_xor(sX,32,64);
    sY += __shfl_xor(sY,16,64); sY += __shfl_xor(sY,32,64);
    sZ += __shfl_xor(sZ,16,64); sZ += __shfl_xor(sZ,32,64);
    if (lane < 16){
      const int f2 = (ntg*16 + lane) - 256;
      aggP[sh][384 + f2*3+0]=sX; aggP[sh][384 + f2*3+1]=sY; aggP[sh][384 + f2*3+2]=sZ;
    }
  }
#undef MFMA_PAIR

  __syncthreads();
  for (int t2=tid; t2<576; t2+=512) aggC[t2] = (aggP[0][t2]+aggP[1][t2]) * (1.0f/128.0f);
  __syncthreads();

  // ---- E1 (disjoint): s-mix partials on tid<256; V-mix on tid 256..447 ----
  if (tid < 256){
    const int o = tid & 127, p = tid >> 7;
    const int c0 = p*96;
    float a0=0.f, a1=0.f, a2=0.f, a3=0.f;
    #pragma unroll 8
    for (int cc=c0; cc<c0+96; cc+=4){
      a0 = fmaf(aggC[cc],   WmixSl[cc*FS+o],     a0);
      a1 = fmaf(aggC[cc+1], WmixSl[(cc+1)*FS+o], a1);
      a2 = fmaf(aggC[cc+2], WmixSl[(cc+2)*FS+o], a2);
      a3 = fmaf(aggC[cc+3], WmixSl[(cc+3)*FS+o], a3);
    }
    sPart[p][o] = (a0+a1)+(a2+a3);
  } else if (tid < 448){
    const int o = tid - 256;            // 0..191
    const int g = o/3, c3 = o - g*3;
    float a0=0.f, a1=0.f, a2=0.f, a3=0.f;
    #pragma unroll 8
    for (int f=0; f<FV; f+=2){
      a0 = fmaf(aggC[192 + f*3+c3],     WmixVl[f*FV+g],        a0);
      a1 = fmaf(aggC[384 + f*3+c3],     WmixVl[(f+FV)*FV+g],   a1);
      a2 = fmaf(aggC[192 + (f+1)*3+c3], WmixVl[(f+1)*FV+g],    a2);
      a3 = fmaf(aggC[384 + (f+1)*3+c3], WmixVl[(f+1+FV)*FV+g], a3);
    }
    vNewL[o] = vIb[o*NN + k] + (a0+a1)+(a2+a3);
  }
  __syncthreads();

  // ---- E2 (disjoint): s-finalize on tid<128; out_v on tid 128..319 ----
  if (tid < FS){
    float sk = sIb[tid*NN + k];
    sNew[tid] = sk + silu_f(sPart[0][tid] + sPart[1][tid]);
  } else if (tid < 320){
    const int o = tid - 128;            // 0..191
    const int g = o/3, c3 = o - g*3;
    float a = comL[c3];
    #pragma unroll 8
    for (int f=0; f<FV; f++) a = fmaf(vNewL[f*3+c3], WoutV[f*FV+g], a);
    outp[(b*NN+k)*FV*3 + o] = a;
  }
  __syncthreads();

  // ---- E3: out_s on tid<128 ----
  if (tid < FS){
    float a0=0.f, a1=0.f, a2=0.f, a3=0.f;
    #pragma unroll 8
    for (int f=0; f<FS; f+=4){
      a0 = fmaf(sNew[f],   WoutS[f*FS+tid],     a0);
      a1 = fmaf(sNew[f+1], WoutS[(f+1)*FS+tid], a1);
      a2 = fmaf(sNew[f+2], WoutS[(f+2)*FS+tid], a2);
      a3 = fmaf(sNew[f+3], WoutS[(f+3)*FS+tid], a3);
    }
    outp[BATCH*NN*FV*3 + (b*NN+k)*FS + tid] = (a0+a1)+(a2+a3);
  }
}

extern "C" void kernel_launch(void* const* d_in, const int* in_sizes, int n_in,
                              void* d_out, int out_size, void* d_ws, size_t ws_size,
                              hipStream_t stream)
{
  const float* x       = (const float*)d_in[0];
  const float* species = (const float*)d_in[1];
  const float* Wr1     = (const float*)d_in[2];
  const float* Wr2     = (const float*)d_in[3];
  const float* Wsv     = (const float*)d_in[4];
  const float* WmixS   = (const float*)d_in[5];
  const float* WmixV   = (const float*)d_in[6];
  const float* WoutS   = (const float*)d_in[7];
  const float* WoutV   = (const float*)d_in[8];
  float* ws  = (float*)d_ws;
  float* out = (float*)d_out;

  float* sB   = ws + OFF_SB;
  float* vB   = ws + OFF_VB;
  float* t1   = ws + OFF_T1;
  u16*   w2b  = (u16*)(ws + OFF_W2B);
  float* rbE  = ws + OFF_RBE;
  float* vhE  = ws + OFF_VHE;

  // layer 0 (specialized) -> sB, vB, t1; also rbE/vhatE + Wr2[layer1] -> bf16
  layer0_kernel<<<BATCH*NN, 320, 0, stream>>>(x, species, Wr1, Wr2, Wsv,
      WmixS, WmixV, sB, vB, t1, w2b, rbE, vhE);

  // layer 1 (final): reads sB/vB/t1 + rbE/vhatE, writes d_out directly
  layer_kernel<<<BATCH*NN, 512, 0, stream>>>(x, sB, vB, t1, rbE, vhE,
      Wr1 + NB*HID, w2b, WmixS + 192*FS, WmixV + 128*FV,
      WoutS, WoutV, out);
}

// Round 13
// 144.953 us; speedup vs baseline: 1.1539x; 1.1539x over previous
//
#include <hip/hip_runtime.h>
#include <math.h>

typedef unsigned short u16;
typedef __attribute__((ext_vector_type(8))) short frag_ab;  // 8 bf16
typedef __attribute__((ext_vector_type(4))) float frag_cd;  // 4 fp32

#define BATCH 8
#define NN 128
#define FS 128
#define FV 64
#define NB 8
#define HID 64
#define ROUT 320
#define HSTRB 72    // hid bf16 LDS row stride (shorts)
#define HSTRF 68    // hid fp32 LDS row stride (floats), layer-0

// ---- ws layout (float offsets); s:[b][f][n], V:[b][f*3+c3][n], t:[b][g][n] ----
#define SZ_S (BATCH*FS*NN)
#define SZ_V (BATCH*FV*3*NN)
#define SZ_T (BATCH*FV*NN)
#define N_W2B (ROUT*HID)            // ushort count (layer-1 Wr2 in bf16)
#define OFF_SB 0
#define OFF_VB (OFF_SB+SZ_S)
#define OFF_T1 (OFF_VB+SZ_V)
#define OFF_W2B (OFF_T1+SZ_T)

__device__ __forceinline__ float silu_f(float x){ return x * (1.0f/(1.0f + __expf(-x))); }

__device__ __forceinline__ u16 f2bf(float x){
  union { float f; unsigned int u; } v; v.f = x;
  unsigned int r = v.u + 0x7fffu + ((v.u >> 16) & 1u);
  return (u16)(r >> 16);
}

// ---------------- Layer 0 (specialized: s=species uniform, V=0, t uniform) ----------------
__global__ __launch_bounds__(320) void layer0_kernel(
    const float* __restrict__ pos,
    const float* __restrict__ species,  // (128)
    const float* __restrict__ Wr1l,     // (8,64) layer0
    const float* __restrict__ Wr2,      // (2,64,320) fp32
    const float* __restrict__ Wsv,      // (2,128,64)
    const float* __restrict__ WmixSl,   // (192,128) layer0
    const float* __restrict__ WmixVl,   // (128,64) layer0
    float* __restrict__ sOut,           // [b][f][n]
    float* __restrict__ vOut,           // [b][f*3+c3][n]
    float* __restrict__ tOut,           // [b][g][n]
    u16*   __restrict__ w2b)            // (320,64) bf16 c-major, layer1
{
  const int tid = threadIdx.x;
  const int b   = blockIdx.x >> 7;
  const int k   = blockIdx.x & 127;

  __shared__ float hidF[128*HSTRF];
  __shared__ float vhx[128], vhy[128], vhz[128];
  __shared__ float colsum[4][64];
  __shared__ float aggS[128];
  __shared__ float aggV1[192];
  __shared__ float sNew[FS];
  __shared__ float t0L[64];

  const float* pb   = pos + b*NN*3;
  const float* Wr2l = Wr2;

  if (tid < 256){
    const int i    = tid & 127;
    const int half = tid >> 7;
    float vx = pb[k*3+0]-pb[i*3+0];
    float vy = pb[k*3+1]-pb[i*3+1];
    float vz = pb[k*3+2]-pb[i*3+2];
    float r = sqrtf(vx*vx+vy*vy+vz*vz) + 1e-8f;
    float inv = 1.0f/r;
    if (half==0){ vhx[i]=vx*inv; vhy[i]=vy*inv; vhz[i]=vz*inv; }
    float u = r*0.2f;
    float env = 0.0f;
    if (u < 1.0f && i != k){
      float u2=u*u, u6=u2*u2*u2;
      env = 1.0f - 28.0f*u6 + 48.0f*u6*u - 21.0f*u6*u2;
    }
    float coef = 0.6324555320336759f * inv * env;
    float th   = r * 0.6283185307179586f;
    float s1 = __sinf(th), c1 = __cosf(th);
    float rb[NB];
    rb[0] = coef*s1;
    float twoc = 2.f*c1, sp = s1, spp = 0.f;
    #pragma unroll
    for(int n=1;n<NB;n++){ float s = twoc*sp - spp; spp = sp; sp = s; rb[n] = coef*s; }
    #pragma unroll
    for(int jg=0;jg<8;jg++){
      const int jgg = half*8 + jg;
      float h0=0.f,h1=0.f,h2=0.f,h3=0.f;
      #pragma unroll
      for(int n=0;n<NB;n++){
        const float* wr = Wr1l + n*HID + jgg*4;
        float rn = rb[n];
        h0 = fmaf(rn, wr[0], h0);
        h1 = fmaf(rn, wr[1], h1);
        h2 = fmaf(rn, wr[2], h2);
        h3 = fmaf(rn, wr[3], h3);
      }
      float4 hh = make_float4(silu_f(h0), silu_f(h1), silu_f(h2), silu_f(h3));
      *(float4*)&hidF[i*HSTRF + jgg*4] = hh;
    }
  } else {
    const int g = tid - 256;   // 0..63
    float a0=0.f, a1=0.f;
    #pragma unroll 8
    for (int c=0; c<FS; c+=2){
      a0 = fmaf(species[c],   Wsv[c*FV+g],     a0);
      a1 = fmaf(species[c+1], Wsv[(c+1)*FV+g], a1);
    }
    t0L[g] = a0+a1;
  }
  __syncthreads();

  if (tid < 256){
    const int j   = tid & 63;
    const int var = tid >> 6;
    float a0 = 0.f, a1 = 0.f;
    if (var == 0){
      #pragma unroll 8
      for (int i=0;i<128;i+=2){ a0 += hidF[i*HSTRF + j]; a1 += hidF[(i+1)*HSTRF + j]; }
    } else {
      const float* wv = (var==1) ? vhx : (var==2) ? vhy : vhz;
      #pragma unroll 8
      for (int i=0;i<128;i+=2){
        a0 = fmaf(hidF[i*HSTRF + j],     wv[i],   a0);
        a1 = fmaf(hidF[(i+1)*HSTRF + j], wv[i+1], a1);
      }
    }
    colsum[var][j] = a0+a1;
  } else if (tid < 276){
    const int t = blockIdx.x*20 + (tid-256);   // 1024*20 = 20480 = N_W2B
    const int j = t & 63, c = t >> 6;
    w2b[t] = f2bf(Wr2[HID*ROUT + j*ROUT + c]);
  }
  __syncthreads();

  if (tid < 128){
    const int c = tid;
    float d0 = 0.f, d1 = 0.f;
    #pragma unroll 8
    for (int j=0;j<HID;j+=2){
      d0 = fmaf(colsum[0][j],   Wr2l[j*ROUT + c],     d0);
      d1 = fmaf(colsum[0][j+1], Wr2l[(j+1)*ROUT + c], d1);
    }
    aggS[c] = species[c] * (d0+d1) * (1.0f/128.0f);
  } else {
    const int idx = tid - 128;          // 0..191
    const int f = idx & 63, c3 = idx >> 6;
    float d0 = 0.f, d1 = 0.f;
    #pragma unroll 8
    for (int j=0;j<HID;j+=2){
      d0 = fmaf(colsum[1+c3][j],   Wr2l[j*ROUT + 192 + f],     d0);
      d1 = fmaf(colsum[1+c3][j+1], Wr2l[(j+1)*ROUT + 192 + f], d1);
    }
    aggV1[f*3+c3] = t0L[f] * (d0+d1) * (1.0f/128.0f);
  }
  __syncthreads();

  if (tid < FS){
    float a0=0.f, a1=0.f, a2=0.f, a3=0.f;
    #pragma unroll 8
    for (int cc=0; cc<128; cc+=4){
      a0 = fmaf(aggS[cc],   WmixSl[cc*FS+tid],     a0);
      a1 = fmaf(aggS[cc+1], WmixSl[(cc+1)*FS+tid], a1);
      a2 = fmaf(aggS[cc+2], WmixSl[(cc+2)*FS+tid], a2);
      a3 = fmaf(aggS[cc+3], WmixSl[(cc+3)*FS+tid], a3);
    }
    float sn = species[tid] + silu_f((a0+a1)+(a2+a3));
    sNew[tid] = sn;
    sOut[(b*FS+tid)*NN + k] = sn;
  } else {
    const int o = tid - 128;            // 0..191
    const int g = o/3, c3 = o - g*3;
    float a0=0.f, a1=0.f;
    #pragma unroll 8
    for (int f=0; f<FV; f+=2){
      a0 = fmaf(aggV1[f*3+c3],     WmixVl[f*FV+g],     a0);
      a1 = fmaf(aggV1[(f+1)*3+c3], WmixVl[(f+1)*FV+g], a1);
    }
    vOut[(b*FV*3 + o)*NN + k] = a0 + a1;
  }
  __syncthreads();
  if (tid < FV){
    const float* Wsv1 = Wsv + FS*FV;
    float a0=0.f, a1=0.f, a2=0.f, a3=0.f;
    #pragma unroll 8
    for (int f=0; f<FS; f+=4){
      a0 = fmaf(sNew[f],   Wsv1[f*FV+tid],     a0);
      a1 = fmaf(sNew[f+1], Wsv1[(f+1)*FV+tid], a1);
      a2 = fmaf(sNew[f+2], Wsv1[(f+2)*FV+tid], a2);
      a3 = fmaf(sNew[f+3], Wsv1[(f+3)*FV+tid], a3);
    }
    tOut[(b*FV+tid)*NN + k] = (a0+a1)+(a2+a3);
  }
}

// ---------------- Layer 1 (final): TWO receivers per block ----------------
// grid = BATCH*NN/2 = 512; block 512 = 8 waves. wave w: wq=w&3 channel group,
// sh=w>>2 sender half. B-frags / factor loads / epilogue weights loaded ONCE,
// applied to both receivers (dual accumulators).
__global__ __launch_bounds__(512) void layer_kernel(
    const float* __restrict__ pos,
    const float* __restrict__ sIn,    // [b][f][n]
    const float* __restrict__ vIn,    // [b][f*3+c3][n]
    const float* __restrict__ tIn,    // [b][g][n]
    const float* __restrict__ Wr1l,   // (8,64) layer1
    const u16*   __restrict__ w2bl,   // (320,64) bf16, c-major
    const float* __restrict__ WmixSl, // (192,128)
    const float* __restrict__ WmixVl, // (128,64)
    const float* __restrict__ WoutS,
    const float* __restrict__ WoutV,
    float* __restrict__ outp)
{
  const int tid  = threadIdx.x;
  const int b    = blockIdx.x >> 6;
  const int k0   = (blockIdx.x & 63) * 2;     // receivers k0, k0+1
  const int w    = tid >> 6;
  const int lane = tid & 63;
  const int col  = lane & 15;
  const int quad = lane >> 4;
  const int wq   = w & 3;
  const int sh   = w >> 2;

  __shared__ u16   hidB[2][128*HSTRB];        // 36.9 KB
  __shared__ float vhx[2][128], vhy[2][128], vhz[2][128];
  __shared__ float aggP[2][2][576];           // [kk][sh][...]; [kk][0] reused as combined
  __shared__ float sPart[2][2][FS];
  __shared__ float sNew[2][FS];
  __shared__ float vNewL[2][192];
  __shared__ float comL[3];

  const float* pb = pos + b*NN*3;

  // ---- phase 0: tid = kk*256 + half*128 + i ----
  {
    const int kk   = tid >> 8;
    const int r2   = tid & 255;
    const int i    = r2 & 127;
    const int half = r2 >> 7;
    const int k    = k0 + kk;
    float vx = pb[k*3+0]-pb[i*3+0];
    float vy = pb[k*3+1]-pb[i*3+1];
    float vz = pb[k*3+2]-pb[i*3+2];
    float r = sqrtf(vx*vx+vy*vy+vz*vz) + 1e-8f;
    float inv = 1.0f/r;
    if (half==0){ vhx[kk][i]=vx*inv; vhy[kk][i]=vy*inv; vhz[kk][i]=vz*inv; }
    float u = r*0.2f;
    float env = 0.0f;
    if (u < 1.0f && i != k){
      float u2=u*u, u6=u2*u2*u2;
      env = 1.0f - 28.0f*u6 + 48.0f*u6*u - 21.0f*u6*u2;
    }
    float coef = 0.6324555320336759f * inv * env;
    float th   = r * 0.6283185307179586f;
    float s1 = __sinf(th), c1 = __cosf(th);
    float rb[NB];
    rb[0] = coef*s1;
    float twoc = 2.f*c1, sp = s1, spp = 0.f;
    #pragma unroll
    for(int n=1;n<NB;n++){ float s = twoc*sp - spp; spp = sp; sp = s; rb[n] = coef*s; }
    u16* hrow = hidB[kk] + i*HSTRB;
    #pragma unroll
    for(int jg=0;jg<8;jg++){
      const int jgg = half*8 + jg;
      float h0=0.f,h1=0.f,h2=0.f,h3=0.f;
      #pragma unroll
      for(int n=0;n<NB;n++){
        const float* wr = Wr1l + n*HID + jgg*4;
        float rn = rb[n];
        h0 = fmaf(rn, wr[0], h0);
        h1 = fmaf(rn, wr[1], h1);
        h2 = fmaf(rn, wr[2], h2);
        h3 = fmaf(rn, wr[3], h3);
      }
      ushort4 uu = make_ushort4(f2bf(silu_f(h0)), f2bf(silu_f(h1)),
                                f2bf(silu_f(h2)), f2bf(silu_f(h3)));
      *(ushort4*)(hrow + jgg*4) = uu;
    }
    if (tid < 3){
      float a0=0.f, a1=0.f;
      for (int n=0;n<NN;n+=2){ a0 += pb[n*3+tid]; a1 += pb[(n+1)*3+tid]; }
      comL[tid] = (a0+a1) * (1.0f/128.0f);
    }
  }
  __syncthreads();

  const float* sIb = sIn + b*FS*NN;
  const float* vIb = vIn + b*FV*3*NN;
  const float* tIb = tIn + b*FV*NN;
  const int i00 = sh*64 + quad*4;

#define MFMA_PAIR(accv, KK, MT) \
    { const int hrow_ = (sh*64 + (MT)*16 + col)*HSTRB + quad*8; \
      frag_ab a0_ = *(const frag_ab*)&hidB[KK][hrow_]; \
      frag_ab a1_ = *(const frag_ab*)&hidB[KK][hrow_ + 32]; \
      accv = __builtin_amdgcn_mfma_f32_16x16x32_bf16(a0_, b0, accv, 0,0,0); \
      accv = __builtin_amdgcn_mfma_f32_16x16x32_bf16(a1_, b1, accv, 0,0,0); }

  // q = 0,1 : m0a (factor = s[i][c], k-independent)
  #pragma unroll
  for (int q=0; q<2; q++){
    const int ntg = q*4 + wq;
    const int c   = ntg*16 + col;
    const u16* wp = w2bl + c*HID + quad*8;
    const frag_ab b0 = *(const frag_ab*)(wp);
    const frag_ab b1 = *(const frag_ab*)(wp + 32);
    const float* fb = sIb + c*NN + i00;
    float sA0 = 0.f, sA1 = 0.f;
    #pragma unroll
    for (int mt=0; mt<4; mt++){
      float4 s4 = *(const float4*)&fb[mt*16];
      frag_cd acc = {0.f,0.f,0.f,0.f};
      MFMA_PAIR(acc, 0, mt);
      sA0 += acc[0]*s4.x + acc[1]*s4.y + acc[2]*s4.z + acc[3]*s4.w;
      frag_cd ac2 = {0.f,0.f,0.f,0.f};
      MFMA_PAIR(ac2, 1, mt);
      sA1 += ac2[0]*s4.x + ac2[1]*s4.y + ac2[2]*s4.z + ac2[3]*s4.w;
    }
    sA0 += __shfl_xor(sA0, 16, 64); sA0 += __shfl_xor(sA0, 32, 64);
    sA1 += __shfl_xor(sA1, 16, 64); sA1 += __shfl_xor(sA1, 32, 64);
    if (lane < 16){ aggP[0][sh][ntg*16+lane] = sA0; aggP[1][sh][ntg*16+lane] = sA1; }
  }
  // q = 2 : m0b (factor = V[i,f,:]·vhat_k[i])
  {
    const int ntg = 8 + wq;
    const int c   = ntg*16 + col;
    const u16* wp = w2bl + c*HID + quad*8;
    const frag_ab b0 = *(const frag_ab*)(wp);
    const frag_ab b1 = *(const frag_ab*)(wp + 32);
    const int f = c - FS;
    const float* fb = vIb + f*3*NN + i00;
    float sA0 = 0.f, sA1 = 0.f;
    #pragma unroll
    for (int mt=0; mt<4; mt++){
      float4 vx4 = *(const float4*)&fb[mt*16];
      float4 vy4 = *(const float4*)&fb[NN + mt*16];
      float4 vz4 = *(const float4*)&fb[2*NN + mt*16];
      {
        float4 hx4 = *(const float4*)&vhx[0][i00 + mt*16];
        float4 hy4 = *(const float4*)&vhy[0][i00 + mt*16];
        float4 hz4 = *(const float4*)&vhz[0][i00 + mt*16];
        frag_cd acc = {0.f,0.f,0.f,0.f};
        MFMA_PAIR(acc, 0, mt);
        sA0 += acc[0]*(vx4.x*hx4.x + vy4.x*hy4.x + vz4.x*hz4.x)
             + acc[1]*(vx4.y*hx4.y + vy4.y*hy4.y + vz4.y*hz4.y)
             + acc[2]*(vx4.z*hx4.z + vy4.z*hy4.z + vz4.z*hz4.z)
             + acc[3]*(vx4.w*hx4.w + vy4.w*hy4.w + vz4.w*hz4.w);
      }
      {
        float4 hx4 = *(const float4*)&vhx[1][i00 + mt*16];
        float4 hy4 = *(const float4*)&vhy[1][i00 + mt*16];
        float4 hz4 = *(const float4*)&vhz[1][i00 + mt*16];
        frag_cd acc = {0.f,0.f,0.f,0.f};
        MFMA_PAIR(acc, 1, mt);
        sA1 += acc[0]*(vx4.x*hx4.x + vy4.x*hy4.x + vz4.x*hz4.x)
             + acc[1]*(vx4.y*hx4.y + vy4.y*hy4.y + vz4.y*hz4.y)
             + acc[2]*(vx4.z*hx4.z + vy4.z*hy4.z + vz4.z*hz4.z)
             + acc[3]*(vx4.w*hx4.w + vy4.w*hy4.w + vz4.w*hz4.w);
      }
    }
    sA0 += __shfl_xor(sA0, 16, 64); sA0 += __shfl_xor(sA0, 32, 64);
    sA1 += __shfl_xor(sA1, 16, 64); sA1 += __shfl_xor(sA1, 32, 64);
    if (lane < 16){ aggP[0][sh][ntg*16+lane] = sA0; aggP[1][sh][ntg*16+lane] = sA1; }
  }
  // q = 3 : m1a (tb = H * t[i,f]; 3 comps via vhat_k)
  {
    const int ntg = 12 + wq;
    const int c   = ntg*16 + col;
    const u16* wp = w2bl + c*HID + quad*8;
    const frag_ab b0 = *(const frag_ab*)(wp);
    const frag_ab b1 = *(const frag_ab*)(wp + 32);
    const int f = c - (FS+FV);
    const float* fb = tIb + f*NN + i00;
    float sX0=0.f,sY0=0.f,sZ0=0.f, sX1=0.f,sY1=0.f,sZ1=0.f;
    #pragma unroll
    for (int mt=0; mt<4; mt++){
      float4 t4 = *(const float4*)&fb[mt*16];
      {
        float4 hx4 = *(const float4*)&vhx[0][i00 + mt*16];
        float4 hy4 = *(const float4*)&vhy[0][i00 + mt*16];
        float4 hz4 = *(const float4*)&vhz[0][i00 + mt*16];
        frag_cd acc = {0.f,0.f,0.f,0.f};
        MFMA_PAIR(acc, 0, mt);
        float t0_=acc[0]*t4.x, t1_=acc[1]*t4.y, t2_=acc[2]*t4.z, t3_=acc[3]*t4.w;
        sX0 += t0_*hx4.x + t1_*hx4.y + t2_*hx4.z + t3_*hx4.w;
        sY0 += t0_*hy4.x + t1_*hy4.y + t2_*hy4.z + t3_*hy4.w;
        sZ0 += t0_*hz4.x + t1_*hz4.y + t2_*hz4.z + t3_*hz4.w;
      }
      {
        float4 hx4 = *(const float4*)&vhx[1][i00 + mt*16];
        float4 hy4 = *(const float4*)&vhy[1][i00 + mt*16];
        float4 hz4 = *(const float4*)&vhz[1][i00 + mt*16];
        frag_cd acc = {0.f,0.f,0.f,0.f};
        MFMA_PAIR(acc, 1, mt);
        float t0_=acc[0]*t4.x, t1_=acc[1]*t4.y, t2_=acc[2]*t4.z, t3_=acc[3]*t4.w;
        sX1 += t0_*hx4.x + t1_*hx4.y + t2_*hx4.z + t3_*hx4.w;
        sY1 += t0_*hy4.x + t1_*hy4.y + t2_*hy4.z + t3_*hy4.w;
        sZ1 += t0_*hz4.x + t1_*hz4.y + t2_*hz4.z + t3_*hz4.w;
      }
    }
    sX0 += __shfl_xor(sX0,16,64); sX0 += __shfl_xor(sX0,32,64);
    sY0 += __shfl_xor(sY0,16,64); sY0 += __shfl_xor(sY0,32,64);
    sZ0 += __shfl_xor(sZ0,16,64); sZ0 += __shfl_xor(sZ0,32,64);
    sX1 += __shfl_xor(sX1,16,64); sX1 += __shfl_xor(sX1,32,64);
    sY1 += __shfl_xor(sY1,16,64); sY1 += __shfl_xor(sY1,32,64);
    sZ1 += __shfl_xor(sZ1,16,64); sZ1 += __shfl_xor(sZ1,32,64);
    if (lane < 16){
      const int f2 = (ntg*16 + lane) - 192;
      aggP[0][sh][192+f2*3+0]=sX0; aggP[0][sh][192+f2*3+1]=sY0; aggP[0][sh][192+f2*3+2]=sZ0;
      aggP[1][sh][192+f2*3+0]=sX1; aggP[1][sh][192+f2*3+1]=sY1; aggP[1][sh][192+f2*3+2]=sZ1;
    }
  }
  // q = 4 : m1b (factor = V[i,f,c3], k-independent; H differs per k)
  {
    const int ntg = 16 + wq;
    const int c   = ntg*16 + col;
    const u16* wp = w2bl + c*HID + quad*8;
    const frag_ab b0 = *(const frag_ab*)(wp);
    const frag_ab b1 = *(const frag_ab*)(wp + 32);
    const int f = c - (FS+2*FV);
    const float* fb = vIb + f*3*NN + i00;
    float sX0=0.f,sY0=0.f,sZ0=0.f, sX1=0.f,sY1=0.f,sZ1=0.f;
    #pragma unroll
    for (int mt=0; mt<4; mt++){
      float4 vx4 = *(const float4*)&fb[mt*16];
      float4 vy4 = *(const float4*)&fb[NN + mt*16];
      float4 vz4 = *(const float4*)&fb[2*NN + mt*16];
      {
        frag_cd acc = {0.f,0.f,0.f,0.f};
        MFMA_PAIR(acc, 0, mt);
        sX0 += acc[0]*vx4.x + acc[1]*vx4.y + acc[2]*vx4.z + acc[3]*vx4.w;
        sY0 += acc[0]*vy4.x + acc[1]*vy4.y + acc[2]*vy4.z + acc[3]*vy4.w;
        sZ0 += acc[0]*vz4.x + acc[1]*vz4.y + acc[2]*vz4.z + acc[3]*vz4.w;
      }
      {
        frag_cd acc = {0.f,0.f,0.f,0.f};
        MFMA_PAIR(acc, 1, mt);
        sX1 += acc[0]*vx4.x + acc[1]*vx4.y + acc[2]*vx4.z + acc[3]*vx4.w;
        sY1 += acc[0]*vy4.x + acc[1]*vy4.y + acc[2]*vy4.z + acc[3]*vy4.w;
        sZ1 += acc[0]*vz4.x + acc[1]*vz4.y + acc[2]*vz4.z + acc[3]*vz4.w;
      }
    }
    sX0 += __shfl_xor(sX0,16,64); sX0 += __shfl_xor(sX0,32,64);
    sY0 += __shfl_xor(sY0,16,64); sY0 += __shfl_xor(sY0,32,64);
    sZ0 += __shfl_xor(sZ0,16,64); sZ0 += __shfl_xor(sZ0,32,64);
    sX1 += __shfl_xor(sX1,16,64); sX1 += __shfl_xor(sX1,32,64);
    sY1 += __shfl_xor(sY1,16,64); sY1 += __shfl_xor(sY1,32,64);
    sZ1 += __shfl_xor(sZ1,16,64); sZ1 += __shfl_xor(sZ1,32,64);
    if (lane < 16){
      const int f2 = (ntg*16 + lane) - 256;
      aggP[0][sh][384+f2*3+0]=sX0; aggP[0][sh][384+f2*3+1]=sY0; aggP[0][sh][384+f2*3+2]=sZ0;
      aggP[1][sh][384+f2*3+0]=sX1; aggP[1][sh][384+f2*3+1]=sY1; aggP[1][sh][384+f2*3+2]=sZ1;
    }
  }
#undef MFMA_PAIR

  __syncthreads();
  // combine sender halves in place: aggP[kk][0][t] = (aggP[kk][0][t]+aggP[kk][1][t])/128
  for (int t2=tid; t2<1152; t2+=512){
    const int kk = (t2 >= 576) ? 1 : 0;
    const int t  = t2 - kk*576;
    aggP[kk][0][t] = (aggP[kk][0][t] + aggP[kk][1][t]) * (1.0f/128.0f);
  }
  __syncthreads();

  // ---- E1: s-mix partials (tid<256) | V-mix (tid 256..447); weights loaded once ----
  if (tid < 256){
    const int o = tid & 127, p = tid >> 7;
    const int c0 = p*96;
    float a00=0.f,a01=0.f, a10=0.f,a11=0.f;
    #pragma unroll 8
    for (int cc=c0; cc<c0+96; cc+=2){
      float w0 = WmixSl[cc*FS+o];
      float w1 = WmixSl[(cc+1)*FS+o];
      a00 = fmaf(aggP[0][0][cc],   w0, a00);
      a01 = fmaf(aggP[0][0][cc+1], w1, a01);
      a10 = fmaf(aggP[1][0][cc],   w0, a10);
      a11 = fmaf(aggP[1][0][cc+1], w1, a11);
    }
    sPart[0][p][o] = a00+a01;
    sPart[1][p][o] = a10+a11;
  } else if (tid < 448){
    const int o = tid - 256;            // 0..191
    const int g = o/3, c3 = o - g*3;
    float a00=0.f,a01=0.f, a10=0.f,a11=0.f;
    #pragma unroll 8
    for (int f=0; f<FV; f++){
      float w0 = WmixVl[f*FV+g];
      float w1 = WmixVl[(f+FV)*FV+g];
      a00 = fmaf(aggP[0][0][192+f*3+c3], w0, a00);
      a01 = fmaf(aggP[0][0][384+f*3+c3], w1, a01);
      a10 = fmaf(aggP[1][0][192+f*3+c3], w0, a10);
      a11 = fmaf(aggP[1][0][384+f*3+c3], w1, a11);
    }
    vNewL[0][o] = vIb[o*NN + k0]     + a00 + a01;
    vNewL[1][o] = vIb[o*NN + k0 + 1] + a10 + a11;
  }
  __syncthreads();

  // ---- E2: s-finalize (tid<128) | out_v (tid 128..319) ----
  if (tid < FS){
    sNew[0][tid] = sIb[tid*NN + k0]     + silu_f(sPart[0][0][tid] + sPart[0][1][tid]);
    sNew[1][tid] = sIb[tid*NN + k0 + 1] + silu_f(sPart[1][0][tid] + sPart[1][1][tid]);
  } else if (tid < 320){
    const int o = tid - 128;            // 0..191
    const int g = o/3, c3 = o - g*3;
    float a0 = comL[c3], a1 = comL[c3];
    #pragma unroll 8
    for (int f=0; f<FV; f++){
      float wv = WoutV[f*FV+g];
      a0 = fmaf(vNewL[0][f*3+c3], wv, a0);
      a1 = fmaf(vNewL[1][f*3+c3], wv, a1);
    }
    outp[(b*NN+k0)*FV*3 + o]     = a0;
    outp[(b*NN+k0+1)*FV*3 + o]   = a1;
  }
  __syncthreads();

  // ---- E3: out_s (tid<128) ----
  if (tid < FS){
    float a00=0.f,a01=0.f, a10=0.f,a11=0.f;
    #pragma unroll 8
    for (int f=0; f<FS; f+=2){
      float w0 = WoutS[f*FS+tid];
      float w1 = WoutS[(f+1)*FS+tid];
      a00 = fmaf(sNew[0][f],   w0, a00);
      a01 = fmaf(sNew[0][f+1], w1, a01);
      a10 = fmaf(sNew[1][f],   w0, a10);
      a11 = fmaf(sNew[1][f+1], w1, a11);
    }
    outp[BATCH*NN*FV*3 + (b*NN+k0)*FS + tid]   = a00+a01;
    outp[BATCH*NN*FV*3 + (b*NN+k0+1)*FS + tid] = a10+a11;
  }
}

extern "C" void kernel_launch(void* const* d_in, const int* in_sizes, int n_in,
                              void* d_out, int out_size, void* d_ws, size_t ws_size,
                              hipStream_t stream)
{
  const float* x       = (const float*)d_in[0];
  const float* species = (const float*)d_in[1];
  const float* Wr1     = (const float*)d_in[2];
  const float* Wr2     = (const float*)d_in[3];
  const float* Wsv     = (const float*)d_in[4];
  const float* WmixS   = (const float*)d_in[5];
  const float* WmixV   = (const float*)d_in[6];
  const float* WoutS   = (const float*)d_in[7];
  const float* WoutV   = (const float*)d_in[8];
  float* ws  = (float*)d_ws;
  float* out = (float*)d_out;

  float* sB  = ws + OFF_SB;
  float* vB  = ws + OFF_VB;
  float* t1  = ws + OFF_T1;
  u16*   w2b = (u16*)(ws + OFF_W2B);

  // layer 0 (specialized) -> sB, vB, t1; also converts Wr2[layer1] -> w2b bf16
  layer0_kernel<<<BATCH*NN, 320, 0, stream>>>(x, species, Wr1, Wr2, Wsv,
      WmixS, WmixV, sB, vB, t1, w2b);

  // layer 1 (final): two receivers per block, writes d_out directly
  layer_kernel<<<BATCH*NN/2, 512, 0, stream>>>(x, sB, vB, t1,
      Wr1 + NB*HID, w2b, WmixS + 192*FS, WmixV + 128*FV,
      WoutS, WoutV, out);
}

// Round 14
// 137.219 us; speedup vs baseline: 1.2189x; 1.0564x over previous
//
#include <hip/hip_runtime.h>
#include <math.h>

typedef unsigned short u16;
typedef __attribute__((ext_vector_type(8))) short frag_ab;  // 8 bf16
typedef __attribute__((ext_vector_type(4))) float frag_cd;  // 4 fp32

#define BATCH 8
#define NN 128
#define FS 128
#define FV 64
#define NB 8
#define HID 64
#define ROUT 320
#define HSTRB 72    // hid bf16 LDS row stride (shorts)

// ---- ws layout (float offsets); s:[b][f][n], V:[b][f*3+c3][n], t:[b][g][n] ----
#define SZ_S (BATCH*FS*NN)
#define SZ_V (BATCH*FV*3*NN)
#define SZ_T (BATCH*FV*NN)
#define N_W2B (ROUT*HID)            // ushort count (layer-1 Wr2 in bf16)
#define OFF_SB 0
#define OFF_VB (OFF_SB+SZ_S)
#define OFF_T1 (OFF_VB+SZ_V)
#define OFF_W2B (OFF_T1+SZ_T)

__device__ __forceinline__ float silu_f(float x){ return x * (1.0f/(1.0f + __expf(-x))); }

__device__ __forceinline__ u16 f2bf(float x){
  union { float f; unsigned int u; } v; v.f = x;
  unsigned int r = v.u + 0x7fffu + ((v.u >> 16) & 1u);
  return (u16)(r >> 16);
}
__device__ __forceinline__ float bf2f(u16 h){
  union { unsigned int u; float f; } v; v.u = ((unsigned int)h) << 16; return v.f;
}

// ---------------- Layer 0 (specialized): TWO receivers per block ----------------
// grid = BATCH*NN/2 = 512; block 512. s=species (uniform), V=0, t=t0L (uniform).
// All weight loads (Wr2, WmixS/V, Wsv) shared across the 2 receivers.
__global__ __launch_bounds__(512) void layer0_kernel(
    const float* __restrict__ pos,
    const float* __restrict__ species,  // (128)
    const float* __restrict__ Wr1l,     // (8,64) layer0
    const float* __restrict__ Wr2,      // (2,64,320) fp32
    const float* __restrict__ Wsv,      // (2,128,64)
    const float* __restrict__ WmixSl,   // (192,128) layer0
    const float* __restrict__ WmixVl,   // (128,64) layer0
    float* __restrict__ sOut,           // [b][f][n]
    float* __restrict__ vOut,           // [b][f*3+c3][n]
    float* __restrict__ tOut,           // [b][g][n]
    u16*   __restrict__ w2b)            // (320,64) bf16 c-major, layer1
{
  const int tid = threadIdx.x;
  const int b   = blockIdx.x >> 6;
  const int k0  = (blockIdx.x & 63) * 2;

  __shared__ u16   hidB[2][128*HSTRB];   // 36.9 KB (bf16)
  __shared__ float vhx[2][128], vhy[2][128], vhz[2][128];
  __shared__ float colsum[2][4][64];
  __shared__ float aggS[2][128];
  __shared__ float dV[2][192];           // raw V-channel projections (t0 applied later)
  __shared__ float sNew[2][128];
  __shared__ float t0L[64];

  const float* pb   = pos + b*NN*3;
  const float* Wr2l = Wr2;               // layer0 fp32 (64,320)

  // ---- phase 0: tid = kk*256 + half*128 + i ----
  {
    const int kk   = tid >> 8;
    const int r2   = tid & 255;
    const int i    = r2 & 127;
    const int half = r2 >> 7;
    const int k    = k0 + kk;
    float vx = pb[k*3+0]-pb[i*3+0];
    float vy = pb[k*3+1]-pb[i*3+1];
    float vz = pb[k*3+2]-pb[i*3+2];
    float r = sqrtf(vx*vx+vy*vy+vz*vz) + 1e-8f;
    float inv = 1.0f/r;
    if (half==0){ vhx[kk][i]=vx*inv; vhy[kk][i]=vy*inv; vhz[kk][i]=vz*inv; }
    float u = r*0.2f;
    float env = 0.0f;
    if (u < 1.0f && i != k){
      float u2=u*u, u6=u2*u2*u2;
      env = 1.0f - 28.0f*u6 + 48.0f*u6*u - 21.0f*u6*u2;
    }
    float coef = 0.6324555320336759f * inv * env;
    float th   = r * 0.6283185307179586f;
    float s1 = __sinf(th), c1 = __cosf(th);
    float rb[NB];
    rb[0] = coef*s1;
    float twoc = 2.f*c1, sp = s1, spp = 0.f;
    #pragma unroll
    for(int n=1;n<NB;n++){ float s = twoc*sp - spp; spp = sp; sp = s; rb[n] = coef*s; }
    u16* hrow = hidB[kk] + i*HSTRB;
    #pragma unroll
    for(int jg=0;jg<8;jg++){
      const int jgg = half*8 + jg;
      float h0=0.f,h1=0.f,h2=0.f,h3=0.f;
      #pragma unroll
      for(int n=0;n<NB;n++){
        const float* wr = Wr1l + n*HID + jgg*4;
        float rn = rb[n];
        h0 = fmaf(rn, wr[0], h0);
        h1 = fmaf(rn, wr[1], h1);
        h2 = fmaf(rn, wr[2], h2);
        h3 = fmaf(rn, wr[3], h3);
      }
      ushort4 uu = make_ushort4(f2bf(silu_f(h0)), f2bf(silu_f(h1)),
                                f2bf(silu_f(h2)), f2bf(silu_f(h3)));
      *(ushort4*)(hrow + jgg*4) = uu;
    }
  }
  __syncthreads();

  // ---- phase A: colsum — tid = kk*256 + var*64 + j (exactly 512 threads) ----
  {
    const int kk  = tid >> 8;
    const int var = (tid >> 6) & 3;
    const int j   = tid & 63;
    const u16* hb = hidB[kk];
    float a0 = 0.f, a1 = 0.f;
    if (var == 0){
      #pragma unroll 8
      for (int i=0;i<128;i+=2){
        a0 += bf2f(hb[i*HSTRB + j]);
        a1 += bf2f(hb[(i+1)*HSTRB + j]);
      }
    } else {
      const float* wv = (var==1) ? vhx[kk] : (var==2) ? vhy[kk] : vhz[kk];
      #pragma unroll 8
      for (int i=0;i<128;i+=2){
        a0 = fmaf(bf2f(hb[i*HSTRB + j]),     wv[i],   a0);
        a1 = fmaf(bf2f(hb[(i+1)*HSTRB + j]), wv[i+1], a1);
      }
    }
    colsum[kk][var][j] = a0+a1;
  }
  __syncthreads();

  // ---- phase B (disjoint): s-proj | V-proj | t0L | w2b conversion ----
  if (tid < 128){
    const int c = tid;
    float d00=0.f,d01=0.f, d10=0.f,d11=0.f;
    #pragma unroll 8
    for (int j=0;j<HID;j+=2){
      float w0 = Wr2l[j*ROUT + c];
      float w1 = Wr2l[(j+1)*ROUT + c];
      d00 = fmaf(colsum[0][0][j],   w0, d00);
      d01 = fmaf(colsum[0][0][j+1], w1, d01);
      d10 = fmaf(colsum[1][0][j],   w0, d10);
      d11 = fmaf(colsum[1][0][j+1], w1, d11);
    }
    float sc = species[c] * (1.0f/128.0f);
    aggS[0][c] = sc * (d00+d01);
    aggS[1][c] = sc * (d10+d11);
  } else if (tid < 320){
    const int o = tid - 128;            // 0..191
    const int f = o & 63, c3 = o >> 6;
    float d00=0.f,d01=0.f, d10=0.f,d11=0.f;
    #pragma unroll 8
    for (int j=0;j<HID;j+=2){
      float w0 = Wr2l[j*ROUT + 192 + f];
      float w1 = Wr2l[(j+1)*ROUT + 192 + f];
      d00 = fmaf(colsum[0][1+c3][j],   w0, d00);
      d01 = fmaf(colsum[0][1+c3][j+1], w1, d01);
      d10 = fmaf(colsum[1][1+c3][j],   w0, d10);
      d11 = fmaf(colsum[1][1+c3][j+1], w1, d11);
    }
    dV[0][f*3+c3] = (d00+d01) * (1.0f/128.0f);
    dV[1][f*3+c3] = (d10+d11) * (1.0f/128.0f);
  } else if (tid < 384){
    const int g = tid - 320;            // 0..63: t0L = species @ Wsv0
    float a0=0.f, a1=0.f;
    #pragma unroll 8
    for (int c=0; c<FS; c+=2){
      a0 = fmaf(species[c],   Wsv[c*FV+g],     a0);
      a1 = fmaf(species[c+1], Wsv[(c+1)*FV+g], a1);
    }
    t0L[g] = a0+a1;
  } else if (tid < 424){
    // convert this block's 40-elem slice of Wr2[layer1] to bf16 (512*40 = 20480)
    const int t = blockIdx.x*40 + (tid-384);
    const int j = t & 63, c = t >> 6;
    w2b[t] = f2bf(Wr2[HID*ROUT + j*ROUT + c]);
  }
  __syncthreads();

  // ---- E1 (disjoint): s update | V update — dual receivers, shared weights ----
  if (tid < FS){
    float a00=0.f,a01=0.f, a10=0.f,a11=0.f;
    #pragma unroll 8
    for (int cc=0; cc<128; cc+=2){
      float w0 = WmixSl[cc*FS+tid];
      float w1 = WmixSl[(cc+1)*FS+tid];
      a00 = fmaf(aggS[0][cc],   w0, a00);
      a01 = fmaf(aggS[0][cc+1], w1, a01);
      a10 = fmaf(aggS[1][cc],   w0, a10);
      a11 = fmaf(aggS[1][cc+1], w1, a11);
    }
    float sn0 = species[tid] + silu_f(a00+a01);
    float sn1 = species[tid] + silu_f(a10+a11);
    sNew[0][tid] = sn0;
    sNew[1][tid] = sn1;
    sOut[(b*FS+tid)*NN + k0]     = sn0;
    sOut[(b*FS+tid)*NN + k0 + 1] = sn1;
  } else if (tid < 320){
    const int o = tid - 128;            // 0..191
    const int g = o/3, c3 = o - g*3;
    float a0=0.f, a1=0.f;
    #pragma unroll 8
    for (int f=0; f<FV; f++){
      float w = WmixVl[f*FV+g];
      float tf = t0L[f];
      a0 = fmaf(tf*dV[0][f*3+c3], w, a0);
      a1 = fmaf(tf*dV[1][f*3+c3], w, a1);
    }
    vOut[(b*FV*3 + o)*NN + k0]     = a0;
    vOut[(b*FV*3 + o)*NN + k0 + 1] = a1;
  }
  __syncthreads();

  // ---- E2: t for layer 1 (from updated s), dual receivers ----
  if (tid < FV){
    const float* Wsv1 = Wsv + FS*FV;
    float a00=0.f,a01=0.f, a10=0.f,a11=0.f;
    #pragma unroll 8
    for (int f=0; f<FS; f+=2){
      float w0 = Wsv1[f*FV+tid];
      float w1 = Wsv1[(f+1)*FV+tid];
      a00 = fmaf(sNew[0][f],   w0, a00);
      a01 = fmaf(sNew[0][f+1], w1, a01);
      a10 = fmaf(sNew[1][f],   w0, a10);
      a11 = fmaf(sNew[1][f+1], w1, a11);
    }
    tOut[(b*FV+tid)*NN + k0]     = (a00+a01);
    tOut[(b*FV+tid)*NN + k0 + 1] = (a10+a11);
  }
}

// ---------------- Layer 1 (final): TWO receivers per block (R13 proven body) ----------------
__global__ __launch_bounds__(512) void layer_kernel(
    const float* __restrict__ pos,
    const float* __restrict__ sIn,    // [b][f][n]
    const float* __restrict__ vIn,    // [b][f*3+c3][n]
    const float* __restrict__ tIn,    // [b][g][n]
    const float* __restrict__ Wr1l,   // (8,64) layer1
    const u16*   __restrict__ w2bl,   // (320,64) bf16, c-major
    const float* __restrict__ WmixSl, // (192,128)
    const float* __restrict__ WmixVl, // (128,64)
    const float* __restrict__ WoutS,
    const float* __restrict__ WoutV,
    float* __restrict__ outp)
{
  const int tid  = threadIdx.x;
  const int b    = blockIdx.x >> 6;
  const int k0   = (blockIdx.x & 63) * 2;     // receivers k0, k0+1
  const int w    = tid >> 6;
  const int lane = tid & 63;
  const int col  = lane & 15;
  const int quad = lane >> 4;
  const int wq   = w & 3;
  const int sh   = w >> 2;

  __shared__ u16   hidB[2][128*HSTRB];        // 36.9 KB
  __shared__ float vhx[2][128], vhy[2][128], vhz[2][128];
  __shared__ float aggP[2][2][576];
  __shared__ float sPart[2][2][FS];
  __shared__ float sNew[2][FS];
  __shared__ float vNewL[2][192];
  __shared__ float comL[3];

  const float* pb = pos + b*NN*3;

  // ---- phase 0: tid = kk*256 + half*128 + i ----
  {
    const int kk   = tid >> 8;
    const int r2   = tid & 255;
    const int i    = r2 & 127;
    const int half = r2 >> 7;
    const int k    = k0 + kk;
    float vx = pb[k*3+0]-pb[i*3+0];
    float vy = pb[k*3+1]-pb[i*3+1];
    float vz = pb[k*3+2]-pb[i*3+2];
    float r = sqrtf(vx*vx+vy*vy+vz*vz) + 1e-8f;
    float inv = 1.0f/r;
    if (half==0){ vhx[kk][i]=vx*inv; vhy[kk][i]=vy*inv; vhz[kk][i]=vz*inv; }
    float u = r*0.2f;
    float env = 0.0f;
    if (u < 1.0f && i != k){
      float u2=u*u, u6=u2*u2*u2;
      env = 1.0f - 28.0f*u6 + 48.0f*u6*u - 21.0f*u6*u2;
    }
    float coef = 0.6324555320336759f * inv * env;
    float th   = r * 0.6283185307179586f;
    float s1 = __sinf(th), c1 = __cosf(th);
    float rb[NB];
    rb[0] = coef*s1;
    float twoc = 2.f*c1, sp = s1, spp = 0.f;
    #pragma unroll
    for(int n=1;n<NB;n++){ float s = twoc*sp - spp; spp = sp; sp = s; rb[n] = coef*s; }
    u16* hrow = hidB[kk] + i*HSTRB;
    #pragma unroll
    for(int jg=0;jg<8;jg++){
      const int jgg = half*8 + jg;
      float h0=0.f,h1=0.f,h2=0.f,h3=0.f;
      #pragma unroll
      for(int n=0;n<NB;n++){
        const float* wr = Wr1l + n*HID + jgg*4;
        float rn = rb[n];
        h0 = fmaf(rn, wr[0], h0);
        h1 = fmaf(rn, wr[1], h1);
        h2 = fmaf(rn, wr[2], h2);
        h3 = fmaf(rn, wr[3], h3);
      }
      ushort4 uu = make_ushort4(f2bf(silu_f(h0)), f2bf(silu_f(h1)),
                                f2bf(silu_f(h2)), f2bf(silu_f(h3)));
      *(ushort4*)(hrow + jgg*4) = uu;
    }
    if (tid < 3){
      float a0=0.f, a1=0.f;
      for (int n=0;n<NN;n+=2){ a0 += pb[n*3+tid]; a1 += pb[(n+1)*3+tid]; }
      comL[tid] = (a0+a1) * (1.0f/128.0f);
    }
  }
  __syncthreads();

  const float* sIb = sIn + b*FS*NN;
  const float* vIb = vIn + b*FV*3*NN;
  const float* tIb = tIn + b*FV*NN;
  const int i00 = sh*64 + quad*4;

#define MFMA_PAIR(accv, KK, MT) \
    { const int hrow_ = (sh*64 + (MT)*16 + col)*HSTRB + quad*8; \
      frag_ab a0_ = *(const frag_ab*)&hidB[KK][hrow_]; \
      frag_ab a1_ = *(const frag_ab*)&hidB[KK][hrow_ + 32]; \
      accv = __builtin_amdgcn_mfma_f32_16x16x32_bf16(a0_, b0, accv, 0,0,0); \
      accv = __builtin_amdgcn_mfma_f32_16x16x32_bf16(a1_, b1, accv, 0,0,0); }

  // q = 0,1 : m0a
  #pragma unroll
  for (int q=0; q<2; q++){
    const int ntg = q*4 + wq;
    const int c   = ntg*16 + col;
    const u16* wp = w2bl + c*HID + quad*8;
    const frag_ab b0 = *(const frag_ab*)(wp);
    const frag_ab b1 = *(const frag_ab*)(wp + 32);
    const float* fb = sIb + c*NN + i00;
    float sA0 = 0.f, sA1 = 0.f;
    #pragma unroll
    for (int mt=0; mt<4; mt++){
      float4 s4 = *(const float4*)&fb[mt*16];
      frag_cd acc = {0.f,0.f,0.f,0.f};
      MFMA_PAIR(acc, 0, mt);
      sA0 += acc[0]*s4.x + acc[1]*s4.y + acc[2]*s4.z + acc[3]*s4.w;
      frag_cd ac2 = {0.f,0.f,0.f,0.f};
      MFMA_PAIR(ac2, 1, mt);
      sA1 += ac2[0]*s4.x + ac2[1]*s4.y + ac2[2]*s4.z + ac2[3]*s4.w;
    }
    sA0 += __shfl_xor(sA0, 16, 64); sA0 += __shfl_xor(sA0, 32, 64);
    sA1 += __shfl_xor(sA1, 16, 64); sA1 += __shfl_xor(sA1, 32, 64);
    if (lane < 16){ aggP[0][sh][ntg*16+lane] = sA0; aggP[1][sh][ntg*16+lane] = sA1; }
  }
  // q = 2 : m0b
  {
    const int ntg = 8 + wq;
    const int c   = ntg*16 + col;
    const u16* wp = w2bl + c*HID + quad*8;
    const frag_ab b0 = *(const frag_ab*)(wp);
    const frag_ab b1 = *(const frag_ab*)(wp + 32);
    const int f = c - FS;
    const float* fb = vIb + f*3*NN + i00;
    float sA0 = 0.f, sA1 = 0.f;
    #pragma unroll
    for (int mt=0; mt<4; mt++){
      float4 vx4 = *(const float4*)&fb[mt*16];
      float4 vy4 = *(const float4*)&fb[NN + mt*16];
      float4 vz4 = *(const float4*)&fb[2*NN + mt*16];
      {
        float4 hx4 = *(const float4*)&vhx[0][i00 + mt*16];
        float4 hy4 = *(const float4*)&vhy[0][i00 + mt*16];
        float4 hz4 = *(const float4*)&vhz[0][i00 + mt*16];
        frag_cd acc = {0.f,0.f,0.f,0.f};
        MFMA_PAIR(acc, 0, mt);
        sA0 += acc[0]*(vx4.x*hx4.x + vy4.x*hy4.x + vz4.x*hz4.x)
             + acc[1]*(vx4.y*hx4.y + vy4.y*hy4.y + vz4.y*hz4.y)
             + acc[2]*(vx4.z*hx4.z + vy4.z*hy4.z + vz4.z*hz4.z)
             + acc[3]*(vx4.w*hx4.w + vy4.w*hy4.w + vz4.w*hz4.w);
      }
      {
        float4 hx4 = *(const float4*)&vhx[1][i00 + mt*16];
        float4 hy4 = *(const float4*)&vhy[1][i00 + mt*16];
        float4 hz4 = *(const float4*)&vhz[1][i00 + mt*16];
        frag_cd acc = {0.f,0.f,0.f,0.f};
        MFMA_PAIR(acc, 1, mt);
        sA1 += acc[0]*(vx4.x*hx4.x + vy4.x*hy4.x + vz4.x*hz4.x)
             + acc[1]*(vx4.y*hx4.y + vy4.y*hy4.y + vz4.y*hz4.y)
             + acc[2]*(vx4.z*hx4.z + vy4.z*hy4.z + vz4.z*hz4.z)
             + acc[3]*(vx4.w*hx4.w + vy4.w*hy4.w + vz4.w*hz4.w);
      }
    }
    sA0 += __shfl_xor(sA0, 16, 64); sA0 += __shfl_xor(sA0, 32, 64);
    sA1 += __shfl_xor(sA1, 16, 64); sA1 += __shfl_xor(sA1, 32, 64);
    if (lane < 16){ aggP[0][sh][ntg*16+lane] = sA0; aggP[1][sh][ntg*16+lane] = sA1; }
  }
  // q = 3 : m1a
  {
    const int ntg = 12 + wq;
    const int c   = ntg*16 + col;
    const u16* wp = w2bl + c*HID + quad*8;
    const frag_ab b0 = *(const frag_ab*)(wp);
    const frag_ab b1 = *(const frag_ab*)(wp + 32);
    const int f = c - (FS+FV);
    const float* fb = tIb + f*NN + i00;
    float sX0=0.f,sY0=0.f,sZ0=0.f, sX1=0.f,sY1=0.f,sZ1=0.f;
    #pragma unroll
    for (int mt=0; mt<4; mt++){
      float4 t4 = *(const float4*)&fb[mt*16];
      {
        float4 hx4 = *(const float4*)&vhx[0][i00 + mt*16];
        float4 hy4 = *(const float4*)&vhy[0][i00 + mt*16];
        float4 hz4 = *(const float4*)&vhz[0][i00 + mt*16];
        frag_cd acc = {0.f,0.f,0.f,0.f};
        MFMA_PAIR(acc, 0, mt);
        float t0_=acc[0]*t4.x, t1_=acc[1]*t4.y, t2_=acc[2]*t4.z, t3_=acc[3]*t4.w;
        sX0 += t0_*hx4.x + t1_*hx4.y + t2_*hx4.z + t3_*hx4.w;
        sY0 += t0_*hy4.x + t1_*hy4.y + t2_*hy4.z + t3_*hy4.w;
        sZ0 += t0_*hz4.x + t1_*hz4.y + t2_*hz4.z + t3_*hz4.w;
      }
      {
        float4 hx4 = *(const float4*)&vhx[1][i00 + mt*16];
        float4 hy4 = *(const float4*)&vhy[1][i00 + mt*16];
        float4 hz4 = *(const float4*)&vhz[1][i00 + mt*16];
        frag_cd acc = {0.f,0.f,0.f,0.f};
        MFMA_PAIR(acc, 1, mt);
        float t0_=acc[0]*t4.x, t1_=acc[1]*t4.y, t2_=acc[2]*t4.z, t3_=acc[3]*t4.w;
        sX1 += t0_*hx4.x + t1_*hx4.y + t2_*hx4.z + t3_*hx4.w;
        sY1 += t0_*hy4.x + t1_*hy4.y + t2_*hy4.z + t3_*hy4.w;
        sZ1 += t0_*hz4.x + t1_*hz4.y + t2_*hz4.z + t3_*hz4.w;
      }
    }
    sX0 += __shfl_xor(sX0,16,64); sX0 += __shfl_xor(sX0,32,64);
    sY0 += __shfl_xor(sY0,16,64); sY0 += __shfl_xor(sY0,32,64);
    sZ0 += __shfl_xor(sZ0,16,64); sZ0 += __shfl_xor(sZ0,32,64);
    sX1 += __shfl_xor(sX1,16,64); sX1 += __shfl_xor(sX1,32,64);
    sY1 += __shfl_xor(sY1,16,64); sY1 += __shfl_xor(sY1,32,64);
    sZ1 += __shfl_xor(sZ1,16,64); sZ1 += __shfl_xor(sZ1,32,64);
    if (lane < 16){
      const int f2 = (ntg*16 + lane) - 192;
      aggP[0][sh][192+f2*3+0]=sX0; aggP[0][sh][192+f2*3+1]=sY0; aggP[0][sh][192+f2*3+2]=sZ0;
      aggP[1][sh][192+f2*3+0]=sX1; aggP[1][sh][192+f2*3+1]=sY1; aggP[1][sh][192+f2*3+2]=sZ1;
    }
  }
  // q = 4 : m1b
  {
    const int ntg = 16 + wq;
    const int c   = ntg*16 + col;
    const u16* wp = w2bl + c*HID + quad*8;
    const frag_ab b0 = *(const frag_ab*)(wp);
    const frag_ab b1 = *(const frag_ab*)(wp + 32);
    const int f = c - (FS+2*FV);
    const float* fb = vIb + f*3*NN + i00;
    float sX0=0.f,sY0=0.f,sZ0=0.f, sX1=0.f,sY1=0.f,sZ1=0.f;
    #pragma unroll
    for (int mt=0; mt<4; mt++){
      float4 vx4 = *(const float4*)&fb[mt*16];
      float4 vy4 = *(const float4*)&fb[NN + mt*16];
      float4 vz4 = *(const float4*)&fb[2*NN + mt*16];
      {
        frag_cd acc = {0.f,0.f,0.f,0.f};
        MFMA_PAIR(acc, 0, mt);
        sX0 += acc[0]*vx4.x + acc[1]*vx4.y + acc[2]*vx4.z + acc[3]*vx4.w;
        sY0 += acc[0]*vy4.x + acc[1]*vy4.y + acc[2]*vy4.z + acc[3]*vy4.w;
        sZ0 += acc[0]*vz4.x + acc[1]*vz4.y + acc[2]*vz4.z + acc[3]*vz4.w;
      }
      {
        frag_cd acc = {0.f,0.f,0.f,0.f};
        MFMA_PAIR(acc, 1, mt);
        sX1 += acc[0]*vx4.x + acc[1]*vx4.y + acc[2]*vx4.z + acc[3]*vx4.w;
        sY1 += acc[0]*vy4.x + acc[1]*vy4.y + acc[2]*vy4.z + acc[3]*vy4.w;
        sZ1 += acc[0]*vz4.x + acc[1]*vz4.y + acc[2]*vz4.z + acc[3]*vz4.w;
      }
    }
    sX0 += __shfl_xor(sX0,16,64); sX0 += __shfl_xor(sX0,32,64);
    sY0 += __shfl_xor(sY0,16,64); sY0 += __shfl_xor(sY0,32,64);
    sZ0 += __shfl_xor(sZ0,16,64); sZ0 += __shfl_xor(sZ0,32,64);
    sX1 += __shfl_xor(sX1,16,64); sX1 += __shfl_xor(sX1,32,64);
    sY1 += __shfl_xor(sY1,16,64); sY1 += __shfl_xor(sY1,32,64);
    sZ1 += __shfl_xor(sZ1,16,64); sZ1 += __shfl_xor(sZ1,32,64);
    if (lane < 16){
      const int f2 = (ntg*16 + lane) - 256;
      aggP[0][sh][384+f2*3+0]=sX0; aggP[0][sh][384+f2*3+1]=sY0; aggP[0][sh][384+f2*3+2]=sZ0;
      aggP[1][sh][384+f2*3+0]=sX1; aggP[1][sh][384+f2*3+1]=sY1; aggP[1][sh][384+f2*3+2]=sZ1;
    }
  }
#undef MFMA_PAIR

  __syncthreads();
  for (int t2=tid; t2<1152; t2+=512){
    const int kk = (t2 >= 576) ? 1 : 0;
    const int t  = t2 - kk*576;
    aggP[kk][0][t] = (aggP[kk][0][t] + aggP[kk][1][t]) * (1.0f/128.0f);
  }
  __syncthreads();

  // ---- E1: s-mix partials (tid<256) | V-mix (tid 256..447) ----
  if (tid < 256){
    const int o = tid & 127, p = tid >> 7;
    const int c0 = p*96;
    float a00=0.f,a01=0.f, a10=0.f,a11=0.f;
    #pragma unroll 8
    for (int cc=c0; cc<c0+96; cc+=2){
      float w0 = WmixSl[cc*FS+o];
      float w1 = WmixSl[(cc+1)*FS+o];
      a00 = fmaf(aggP[0][0][cc],   w0, a00);
      a01 = fmaf(aggP[0][0][cc+1], w1, a01);
      a10 = fmaf(aggP[1][0][cc],   w0, a10);
      a11 = fmaf(aggP[1][0][cc+1], w1, a11);
    }
    sPart[0][p][o] = a00+a01;
    sPart[1][p][o] = a10+a11;
  } else if (tid < 448){
    const int o = tid - 256;
    const int g = o/3, c3 = o - g*3;
    float a00=0.f,a01=0.f, a10=0.f,a11=0.f;
    #pragma unroll 8
    for (int f=0; f<FV; f++){
      float w0 = WmixVl[f*FV+g];
      float w1 = WmixVl[(f+FV)*FV+g];
      a00 = fmaf(aggP[0][0][192+f*3+c3], w0, a00);
      a01 = fmaf(aggP[0][0][384+f*3+c3], w1, a01);
      a10 = fmaf(aggP[1][0][192+f*3+c3], w0, a10);
      a11 = fmaf(aggP[1][0][384+f*3+c3], w1, a11);
    }
    vNewL[0][o] = vIb[o*NN + k0]     + a00 + a01;
    vNewL[1][o] = vIb[o*NN + k0 + 1] + a10 + a11;
  }
  __syncthreads();

  // ---- E2: s-finalize (tid<128) | out_v (tid 128..319) ----
  if (tid < FS){
    sNew[0][tid] = sIb[tid*NN + k0]     + silu_f(sPart[0][0][tid] + sPart[0][1][tid]);
    sNew[1][tid] = sIb[tid*NN + k0 + 1] + silu_f(sPart[1][0][tid] + sPart[1][1][tid]);
  } else if (tid < 320){
    const int o = tid - 128;
    const int g = o/3, c3 = o - g*3;
    float a0 = comL[c3], a1 = comL[c3];
    #pragma unroll 8
    for (int f=0; f<FV; f++){
      float wv = WoutV[f*FV+g];
      a0 = fmaf(vNewL[0][f*3+c3], wv, a0);
      a1 = fmaf(vNewL[1][f*3+c3], wv, a1);
    }
    outp[(b*NN+k0)*FV*3 + o]     = a0;
    outp[(b*NN+k0+1)*FV*3 + o]   = a1;
  }
  __syncthreads();

  // ---- E3: out_s (tid<128) ----
  if (tid < FS){
    float a00=0.f,a01=0.f, a10=0.f,a11=0.f;
    #pragma unroll 8
    for (int f=0; f<FS; f+=2){
      float w0 = WoutS[f*FS+tid];
      float w1 = WoutS[(f+1)*FS+tid];
      a00 = fmaf(sNew[0][f],   w0, a00);
      a01 = fmaf(sNew[0][f+1], w1, a01);
      a10 = fmaf(sNew[1][f],   w0, a10);
      a11 = fmaf(sNew[1][f+1], w1, a11);
    }
    outp[BATCH*NN*FV*3 + (b*NN+k0)*FS + tid]   = a00+a01;
    outp[BATCH*NN*FV*3 + (b*NN+k0+1)*FS + tid] = a10+a11;
  }
}

extern "C" void kernel_launch(void* const* d_in, const int* in_sizes, int n_in,
                              void* d_out, int out_size, void* d_ws, size_t ws_size,
                              hipStream_t stream)
{
  const float* x       = (const float*)d_in[0];
  const float* species = (const float*)d_in[1];
  const float* Wr1     = (const float*)d_in[2];
  const float* Wr2     = (const float*)d_in[3];
  const float* Wsv     = (const float*)d_in[4];
  const float* WmixS   = (const float*)d_in[5];
  const float* WmixV   = (const float*)d_in[6];
  const float* WoutS   = (const float*)d_in[7];
  const float* WoutV   = (const float*)d_in[8];
  float* ws  = (float*)d_ws;
  float* out = (float*)d_out;

  float* sB  = ws + OFF_SB;
  float* vB  = ws + OFF_VB;
  float* t1  = ws + OFF_T1;
  u16*   w2b = (u16*)(ws + OFF_W2B);

  // layer 0 (specialized, 2 receivers/block) -> sB, vB, t1; also Wr2[layer1] -> w2b bf16
  layer0_kernel<<<BATCH*NN/2, 512, 0, stream>>>(x, species, Wr1, Wr2, Wsv,
      WmixS, WmixV, sB, vB, t1, w2b);

  // layer 1 (final, 2 receivers/block): writes d_out directly
  layer_kernel<<<BATCH*NN/2, 512, 0, stream>>>(x, sB, vB, t1,
      Wr1 + NB*HID, w2b, WmixS + 192*FS, WmixV + 128*FV,
      WoutS, WoutV, out);
}

// Round 15
// 127.735 us; speedup vs baseline: 1.3094x; 1.0742x over previous
//
#include <hip/hip_runtime.h>
#include <math.h>

typedef unsigned short u16;
typedef __attribute__((ext_vector_type(8))) short frag_ab;  // 8 bf16
typedef __attribute__((ext_vector_type(4))) float frag_cd;  // 4 fp32

#define BATCH 8
#define NN 128
#define FS 128
#define FV 64
#define NB 8
#define HID 64
#define ROUT 320
#define HSTRB 72    // hid bf16 LDS row stride (shorts)

// ---- ws layout (float offsets); s:[b][f][n], V:[b][f*3+c3][n], t:[b][g][n] ----
#define SZ_S (BATCH*FS*NN)
#define SZ_V (BATCH*FV*3*NN)
#define SZ_T (BATCH*FV*NN)
#define N_W2B (ROUT*HID)            // ushort count (layer-1 Wr2 in bf16)
#define OFF_SB 0
#define OFF_VB (OFF_SB+SZ_S)
#define OFF_T1 (OFF_VB+SZ_V)
#define OFF_W2B (OFF_T1+SZ_T)

__device__ __forceinline__ float silu_f(float x){ return x * (1.0f/(1.0f + __expf(-x))); }

__device__ __forceinline__ u16 f2bf(float x){
  union { float f; unsigned int u; } v; v.f = x;
  unsigned int r = v.u + 0x7fffu + ((v.u >> 16) & 1u);
  return (u16)(r >> 16);
}
__device__ __forceinline__ float bf2f(u16 h){
  union { unsigned int u; float f; } v; v.u = ((unsigned int)h) << 16; return v.f;
}

// ---------------- Layer 0 (specialized): TWO receivers per block (R14 proven) ----------------
__global__ __launch_bounds__(512) void layer0_kernel(
    const float* __restrict__ pos,
    const float* __restrict__ species,  // (128)
    const float* __restrict__ Wr1l,     // (8,64) layer0
    const float* __restrict__ Wr2,      // (2,64,320) fp32
    const float* __restrict__ Wsv,      // (2,128,64)
    const float* __restrict__ WmixSl,   // (192,128) layer0
    const float* __restrict__ WmixVl,   // (128,64) layer0
    float* __restrict__ sOut,           // [b][f][n]
    float* __restrict__ vOut,           // [b][f*3+c3][n]
    float* __restrict__ tOut,           // [b][g][n]
    u16*   __restrict__ w2b)            // (320,64) bf16 c-major, layer1
{
  const int tid = threadIdx.x;
  const int b   = blockIdx.x >> 6;
  const int k0  = (blockIdx.x & 63) * 2;

  __shared__ u16   hidB[2][128*HSTRB];
  __shared__ float vhx[2][128], vhy[2][128], vhz[2][128];
  __shared__ float colsum[2][4][64];
  __shared__ float aggS[2][128];
  __shared__ float dV[2][192];
  __shared__ float sNew[2][128];
  __shared__ float t0L[64];

  const float* pb   = pos + b*NN*3;
  const float* Wr2l = Wr2;

  {
    const int kk   = tid >> 8;
    const int r2   = tid & 255;
    const int i    = r2 & 127;
    const int half = r2 >> 7;
    const int k    = k0 + kk;
    float vx = pb[k*3+0]-pb[i*3+0];
    float vy = pb[k*3+1]-pb[i*3+1];
    float vz = pb[k*3+2]-pb[i*3+2];
    float r = sqrtf(vx*vx+vy*vy+vz*vz) + 1e-8f;
    float inv = 1.0f/r;
    if (half==0){ vhx[kk][i]=vx*inv; vhy[kk][i]=vy*inv; vhz[kk][i]=vz*inv; }
    float u = r*0.2f;
    float env = 0.0f;
    if (u < 1.0f && i != k){
      float u2=u*u, u6=u2*u2*u2;
      env = 1.0f - 28.0f*u6 + 48.0f*u6*u - 21.0f*u6*u2;
    }
    float coef = 0.6324555320336759f * inv * env;
    float th   = r * 0.6283185307179586f;
    float s1 = __sinf(th), c1 = __cosf(th);
    float rb[NB];
    rb[0] = coef*s1;
    float twoc = 2.f*c1, sp = s1, spp = 0.f;
    #pragma unroll
    for(int n=1;n<NB;n++){ float s = twoc*sp - spp; spp = sp; sp = s; rb[n] = coef*s; }
    u16* hrow = hidB[kk] + i*HSTRB;
    #pragma unroll
    for(int jg=0;jg<8;jg++){
      const int jgg = half*8 + jg;
      float h0=0.f,h1=0.f,h2=0.f,h3=0.f;
      #pragma unroll
      for(int n=0;n<NB;n++){
        const float* wr = Wr1l + n*HID + jgg*4;
        float rn = rb[n];
        h0 = fmaf(rn, wr[0], h0);
        h1 = fmaf(rn, wr[1], h1);
        h2 = fmaf(rn, wr[2], h2);
        h3 = fmaf(rn, wr[3], h3);
      }
      ushort4 uu = make_ushort4(f2bf(silu_f(h0)), f2bf(silu_f(h1)),
                                f2bf(silu_f(h2)), f2bf(silu_f(h3)));
      *(ushort4*)(hrow + jgg*4) = uu;
    }
  }
  __syncthreads();

  {
    const int kk  = tid >> 8;
    const int var = (tid >> 6) & 3;
    const int j   = tid & 63;
    const u16* hb = hidB[kk];
    float a0 = 0.f, a1 = 0.f;
    if (var == 0){
      #pragma unroll 8
      for (int i=0;i<128;i+=2){
        a0 += bf2f(hb[i*HSTRB + j]);
        a1 += bf2f(hb[(i+1)*HSTRB + j]);
      }
    } else {
      const float* wv = (var==1) ? vhx[kk] : (var==2) ? vhy[kk] : vhz[kk];
      #pragma unroll 8
      for (int i=0;i<128;i+=2){
        a0 = fmaf(bf2f(hb[i*HSTRB + j]),     wv[i],   a0);
        a1 = fmaf(bf2f(hb[(i+1)*HSTRB + j]), wv[i+1], a1);
      }
    }
    colsum[kk][var][j] = a0+a1;
  }
  __syncthreads();

  if (tid < 128){
    const int c = tid;
    float d00=0.f,d01=0.f, d10=0.f,d11=0.f;
    #pragma unroll 8
    for (int j=0;j<HID;j+=2){
      float w0 = Wr2l[j*ROUT + c];
      float w1 = Wr2l[(j+1)*ROUT + c];
      d00 = fmaf(colsum[0][0][j],   w0, d00);
      d01 = fmaf(colsum[0][0][j+1], w1, d01);
      d10 = fmaf(colsum[1][0][j],   w0, d10);
      d11 = fmaf(colsum[1][0][j+1], w1, d11);
    }
    float sc = species[c] * (1.0f/128.0f);
    aggS[0][c] = sc * (d00+d01);
    aggS[1][c] = sc * (d10+d11);
  } else if (tid < 320){
    const int o = tid - 128;
    const int f = o & 63, c3 = o >> 6;
    float d00=0.f,d01=0.f, d10=0.f,d11=0.f;
    #pragma unroll 8
    for (int j=0;j<HID;j+=2){
      float w0 = Wr2l[j*ROUT + 192 + f];
      float w1 = Wr2l[(j+1)*ROUT + 192 + f];
      d00 = fmaf(colsum[0][1+c3][j],   w0, d00);
      d01 = fmaf(colsum[0][1+c3][j+1], w1, d01);
      d10 = fmaf(colsum[1][1+c3][j],   w0, d10);
      d11 = fmaf(colsum[1][1+c3][j+1], w1, d11);
    }
    dV[0][f*3+c3] = (d00+d01) * (1.0f/128.0f);
    dV[1][f*3+c3] = (d10+d11) * (1.0f/128.0f);
  } else if (tid < 384){
    const int g = tid - 320;
    float a0=0.f, a1=0.f;
    #pragma unroll 8
    for (int c=0; c<FS; c+=2){
      a0 = fmaf(species[c],   Wsv[c*FV+g],     a0);
      a1 = fmaf(species[c+1], Wsv[(c+1)*FV+g], a1);
    }
    t0L[g] = a0+a1;
  } else if (tid < 424){
    const int t = blockIdx.x*40 + (tid-384);
    const int j = t & 63, c = t >> 6;
    w2b[t] = f2bf(Wr2[HID*ROUT + j*ROUT + c]);
  }
  __syncthreads();

  if (tid < FS){
    float a00=0.f,a01=0.f, a10=0.f,a11=0.f;
    #pragma unroll 8
    for (int cc=0; cc<128; cc+=2){
      float w0 = WmixSl[cc*FS+tid];
      float w1 = WmixSl[(cc+1)*FS+tid];
      a00 = fmaf(aggS[0][cc],   w0, a00);
      a01 = fmaf(aggS[0][cc+1], w1, a01);
      a10 = fmaf(aggS[1][cc],   w0, a10);
      a11 = fmaf(aggS[1][cc+1], w1, a11);
    }
    float sn0 = species[tid] + silu_f(a00+a01);
    float sn1 = species[tid] + silu_f(a10+a11);
    sNew[0][tid] = sn0;
    sNew[1][tid] = sn1;
    sOut[(b*FS+tid)*NN + k0]     = sn0;
    sOut[(b*FS+tid)*NN + k0 + 1] = sn1;
  } else if (tid < 320){
    const int o = tid - 128;
    const int g = o/3, c3 = o - g*3;
    float a0=0.f, a1=0.f;
    #pragma unroll 8
    for (int f=0; f<FV; f++){
      float w = WmixVl[f*FV+g];
      float tf = t0L[f];
      a0 = fmaf(tf*dV[0][f*3+c3], w, a0);
      a1 = fmaf(tf*dV[1][f*3+c3], w, a1);
    }
    vOut[(b*FV*3 + o)*NN + k0]     = a0;
    vOut[(b*FV*3 + o)*NN + k0 + 1] = a1;
  }
  __syncthreads();

  if (tid < FV){
    const float* Wsv1 = Wsv + FS*FV;
    float a00=0.f,a01=0.f, a10=0.f,a11=0.f;
    #pragma unroll 8
    for (int f=0; f<FS; f+=2){
      float w0 = Wsv1[f*FV+tid];
      float w1 = Wsv1[(f+1)*FV+tid];
      a00 = fmaf(sNew[0][f],   w0, a00);
      a01 = fmaf(sNew[0][f+1], w1, a01);
      a10 = fmaf(sNew[1][f],   w0, a10);
      a11 = fmaf(sNew[1][f+1], w1, a11);
    }
    tOut[(b*FV+tid)*NN + k0]     = (a00+a01);
    tOut[(b*FV+tid)*NN + k0 + 1] = (a10+a11);
  }
}

// ---------------- Layer 1 (final): FOUR receivers per block ----------------
// grid = BATCH*NN/4 = 256 (1 block/CU); block 512 = 8 waves.
// wave w: wq=w&3 channel group, sh=w>>2 sender half. All B-frags, factor loads,
// and epilogue weights loaded once per block, applied to 4 receivers.
__global__ __launch_bounds__(512) void layer_kernel(
    const float* __restrict__ pos,
    const float* __restrict__ sIn,    // [b][f][n]
    const float* __restrict__ vIn,    // [b][f*3+c3][n]
    const float* __restrict__ tIn,    // [b][g][n]
    const float* __restrict__ Wr1l,   // (8,64) layer1
    const u16*   __restrict__ w2bl,   // (320,64) bf16, c-major
    const float* __restrict__ WmixSl, // (192,128)
    const float* __restrict__ WmixVl, // (128,64)
    const float* __restrict__ WoutS,
    const float* __restrict__ WoutV,
    float* __restrict__ outp)
{
  const int tid  = threadIdx.x;
  const int b    = blockIdx.x >> 5;
  const int k0   = (blockIdx.x & 31) * 4;     // receivers k0..k0+3
  const int w    = tid >> 6;
  const int lane = tid & 63;
  const int col  = lane & 15;
  const int quad = lane >> 4;
  const int wq   = w & 3;
  const int sh   = w >> 2;

  __shared__ u16   hidB[4][128*HSTRB];        // 73.7 KB
  __shared__ float vhx[4][128], vhy[4][128], vhz[4][128];
  __shared__ float aggP[4][2][576];           // 18.4 KB
  __shared__ float sPart[4][2][FS];
  __shared__ float sNew[4][FS];
  __shared__ float vNewL[4][192];
  __shared__ float comL[3];

  const float* pb = pos + b*NN*3;

  // ---- phase 0: tid = kk*128 + i; full hid row per thread ----
  {
    const int kk = tid >> 7;
    const int i  = tid & 127;
    const int k  = k0 + kk;
    float vx = pb[k*3+0]-pb[i*3+0];
    float vy = pb[k*3+1]-pb[i*3+1];
    float vz = pb[k*3+2]-pb[i*3+2];
    float r = sqrtf(vx*vx+vy*vy+vz*vz) + 1e-8f;
    float inv = 1.0f/r;
    vhx[kk][i]=vx*inv; vhy[kk][i]=vy*inv; vhz[kk][i]=vz*inv;
    float u = r*0.2f;
    float env = 0.0f;
    if (u < 1.0f && i != k){
      float u2=u*u, u6=u2*u2*u2;
      env = 1.0f - 28.0f*u6 + 48.0f*u6*u - 21.0f*u6*u2;
    }
    float coef = 0.6324555320336759f * inv * env;
    float th   = r * 0.6283185307179586f;
    float s1 = __sinf(th), c1 = __cosf(th);
    float rb[NB];
    rb[0] = coef*s1;
    float twoc = 2.f*c1, sp = s1, spp = 0.f;
    #pragma unroll
    for(int n=1;n<NB;n++){ float s = twoc*sp - spp; spp = sp; sp = s; rb[n] = coef*s; }
    u16* hrow = hidB[kk] + i*HSTRB;
    #pragma unroll
    for(int jg=0;jg<16;jg++){
      float h0=0.f,h1=0.f,h2=0.f,h3=0.f;
      #pragma unroll
      for(int n=0;n<NB;n++){
        const float* wr = Wr1l + n*HID + jg*4;
        float rn = rb[n];
        h0 = fmaf(rn, wr[0], h0);
        h1 = fmaf(rn, wr[1], h1);
        h2 = fmaf(rn, wr[2], h2);
        h3 = fmaf(rn, wr[3], h3);
      }
      ushort4 uu = make_ushort4(f2bf(silu_f(h0)), f2bf(silu_f(h1)),
                                f2bf(silu_f(h2)), f2bf(silu_f(h3)));
      *(ushort4*)(hrow + jg*4) = uu;
    }
    if (tid < 3){
      float a0=0.f, a1=0.f;
      for (int n=0;n<NN;n+=2){ a0 += pb[n*3+tid]; a1 += pb[(n+1)*3+tid]; }
      comL[tid] = (a0+a1) * (1.0f/128.0f);
    }
  }
  __syncthreads();

  const float* sIb = sIn + b*FS*NN;
  const float* vIb = vIn + b*FV*3*NN;
  const float* tIb = tIn + b*FV*NN;
  const int i00 = sh*64 + quad*4;

#define MFMA_PAIR(accv, KK, MT) \
    { const int hrow_ = (sh*64 + (MT)*16 + col)*HSTRB + quad*8; \
      frag_ab a0_ = *(const frag_ab*)&hidB[KK][hrow_]; \
      frag_ab a1_ = *(const frag_ab*)&hidB[KK][hrow_ + 32]; \
      accv = __builtin_amdgcn_mfma_f32_16x16x32_bf16(a0_, b0, accv, 0,0,0); \
      accv = __builtin_amdgcn_mfma_f32_16x16x32_bf16(a1_, b1, accv, 0,0,0); }

  // q = 0,1 : m0a (factor = s[i][c], k-independent)
  #pragma unroll
  for (int q=0; q<2; q++){
    const int ntg = q*4 + wq;
    const int c   = ntg*16 + col;
    const u16* wp = w2bl + c*HID + quad*8;
    const frag_ab b0 = *(const frag_ab*)(wp);
    const frag_ab b1 = *(const frag_ab*)(wp + 32);
    const float* fb = sIb + c*NN + i00;
    float sA[4] = {0.f,0.f,0.f,0.f};
    #pragma unroll
    for (int mt=0; mt<4; mt++){
      float4 s4 = *(const float4*)&fb[mt*16];
      #pragma unroll
      for (int kk=0; kk<4; kk++){
        frag_cd acc = {0.f,0.f,0.f,0.f};
        MFMA_PAIR(acc, kk, mt);
        sA[kk] += acc[0]*s4.x + acc[1]*s4.y + acc[2]*s4.z + acc[3]*s4.w;
      }
    }
    #pragma unroll
    for (int kk=0; kk<4; kk++){
      float v = sA[kk];
      v += __shfl_xor(v, 16, 64); v += __shfl_xor(v, 32, 64);
      if (lane < 16) aggP[kk][sh][ntg*16+lane] = v;
    }
  }
  // q = 2 : m0b (factor = V[i,f,:]·vhat_k[i])
  {
    const int ntg = 8 + wq;
    const int c   = ntg*16 + col;
    const u16* wp = w2bl + c*HID + quad*8;
    const frag_ab b0 = *(const frag_ab*)(wp);
    const frag_ab b1 = *(const frag_ab*)(wp + 32);
    const int f = c - FS;
    const float* fb = vIb + f*3*NN + i00;
    float sA[4] = {0.f,0.f,0.f,0.f};
    #pragma unroll
    for (int mt=0; mt<4; mt++){
      float4 vx4 = *(const float4*)&fb[mt*16];
      float4 vy4 = *(const float4*)&fb[NN + mt*16];
      float4 vz4 = *(const float4*)&fb[2*NN + mt*16];
      #pragma unroll
      for (int kk=0; kk<4; kk++){
        float4 hx4 = *(const float4*)&vhx[kk][i00 + mt*16];
        float4 hy4 = *(const float4*)&vhy[kk][i00 + mt*16];
        float4 hz4 = *(const float4*)&vhz[kk][i00 + mt*16];
        frag_cd acc = {0.f,0.f,0.f,0.f};
        MFMA_PAIR(acc, kk, mt);
        sA[kk] += acc[0]*(vx4.x*hx4.x + vy4.x*hy4.x + vz4.x*hz4.x)
                + acc[1]*(vx4.y*hx4.y + vy4.y*hy4.y + vz4.y*hz4.y)
                + acc[2]*(vx4.z*hx4.z + vy4.z*hy4.z + vz4.z*hz4.z)
                + acc[3]*(vx4.w*hx4.w + vy4.w*hy4.w + vz4.w*hz4.w);
      }
    }
    #pragma unroll
    for (int kk=0; kk<4; kk++){
      float v = sA[kk];
      v += __shfl_xor(v, 16, 64); v += __shfl_xor(v, 32, 64);
      if (lane < 16) aggP[kk][sh][ntg*16+lane] = v;
    }
  }
  // q = 3 : m1a (tb = H * t[i,f]; 3 comps via vhat_k)
  {
    const int ntg = 12 + wq;
    const int c   = ntg*16 + col;
    const u16* wp = w2bl + c*HID + quad*8;
    const frag_ab b0 = *(const frag_ab*)(wp);
    const frag_ab b1 = *(const frag_ab*)(wp + 32);
    const int f = c - (FS+FV);
    const float* fb = tIb + f*NN + i00;
    float sX[4]={0.f,0.f,0.f,0.f}, sY[4]={0.f,0.f,0.f,0.f}, sZ[4]={0.f,0.f,0.f,0.f};
    #pragma unroll
    for (int mt=0; mt<4; mt++){
      float4 t4 = *(const float4*)&fb[mt*16];
      #pragma unroll
      for (int kk=0; kk<4; kk++){
        float4 hx4 = *(const float4*)&vhx[kk][i00 + mt*16];
        float4 hy4 = *(const float4*)&vhy[kk][i00 + mt*16];
        float4 hz4 = *(const float4*)&vhz[kk][i00 + mt*16];
        frag_cd acc = {0.f,0.f,0.f,0.f};
        MFMA_PAIR(acc, kk, mt);
        float t0_=acc[0]*t4.x, t1_=acc[1]*t4.y, t2_=acc[2]*t4.z, t3_=acc[3]*t4.w;
        sX[kk] += t0_*hx4.x + t1_*hx4.y + t2_*hx4.z + t3_*hx4.w;
        sY[kk] += t0_*hy4.x + t1_*hy4.y + t2_*hy4.z + t3_*hy4.w;
        sZ[kk] += t0_*hz4.x + t1_*hz4.y + t2_*hz4.z + t3_*hz4.w;
      }
    }
    #pragma unroll
    for (int kk=0; kk<4; kk++){
      float x = sX[kk]; x += __shfl_xor(x,16,64); x += __shfl_xor(x,32,64);
      float y = sY[kk]; y += __shfl_xor(y,16,64); y += __shfl_xor(y,32,64);
      float z = sZ[kk]; z += __shfl_xor(z,16,64); z += __shfl_xor(z,32,64);
      if (lane < 16){
        const int f2 = (ntg*16 + lane) - 192;
        aggP[kk][sh][192+f2*3+0]=x; aggP[kk][sh][192+f2*3+1]=y; aggP[kk][sh][192+f2*3+2]=z;
      }
    }
  }
  // q = 4 : m1b (factor = V[i,f,c3], k-independent; H differs per k)
  {
    const int ntg = 16 + wq;
    const int c   = ntg*16 + col;
    const u16* wp = w2bl + c*HID + quad*8;
    const frag_ab b0 = *(const frag_ab*)(wp);
    const frag_ab b1 = *(const frag_ab*)(wp + 32);
    const int f = c - (FS+2*FV);
    const float* fb = vIb + f*3*NN + i00;
    float sX[4]={0.f,0.f,0.f,0.f}, sY[4]={0.f,0.f,0.f,0.f}, sZ[4]={0.f,0.f,0.f,0.f};
    #pragma unroll
    for (int mt=0; mt<4; mt++){
      float4 vx4 = *(const float4*)&fb[mt*16];
      float4 vy4 = *(const float4*)&fb[NN + mt*16];
      float4 vz4 = *(const float4*)&fb[2*NN + mt*16];
      #pragma unroll
      for (int kk=0; kk<4; kk++){
        frag_cd acc = {0.f,0.f,0.f,0.f};
        MFMA_PAIR(acc, kk, mt);
        sX[kk] += acc[0]*vx4.x + acc[1]*vx4.y + acc[2]*vx4.z + acc[3]*vx4.w;
        sY[kk] += acc[0]*vy4.x + acc[1]*vy4.y + acc[2]*vy4.z + acc[3]*vy4.w;
        sZ[kk] += acc[0]*vz4.x + acc[1]*vz4.y + acc[2]*vz4.z + acc[3]*vz4.w;
      }
    }
    #pragma unroll
    for (int kk=0; kk<4; kk++){
      float x = sX[kk]; x += __shfl_xor(x,16,64); x += __shfl_xor(x,32,64);
      float y = sY[kk]; y += __shfl_xor(y,16,64); y += __shfl_xor(y,32,64);
      float z = sZ[kk]; z += __shfl_xor(z,16,64); z += __shfl_xor(z,32,64);
      if (lane < 16){
        const int f2 = (ntg*16 + lane) - 256;
        aggP[kk][sh][384+f2*3+0]=x; aggP[kk][sh][384+f2*3+1]=y; aggP[kk][sh][384+f2*3+2]=z;
      }
    }
  }
#undef MFMA_PAIR

  __syncthreads();
  for (int t2=tid; t2<2304; t2+=512){
    const int kk = t2 / 576;
    const int t  = t2 - kk*576;
    aggP[kk][0][t] = (aggP[kk][0][t] + aggP[kk][1][t]) * (1.0f/128.0f);
  }
  __syncthreads();

  // ---- E1: s-mix partials (tid<256) | V-mix (tid 256..447); weights loaded once ----
  if (tid < 256){
    const int o = tid & 127, p = tid >> 7;
    const int c0 = p*96;
    float a0=0.f,a1=0.f,a2=0.f,a3=0.f;
    #pragma unroll 8
    for (int cc=c0; cc<c0+96; cc++){
      float w0 = WmixSl[cc*FS+o];
      a0 = fmaf(aggP[0][0][cc], w0, a0);
      a1 = fmaf(aggP[1][0][cc], w0, a1);
      a2 = fmaf(aggP[2][0][cc], w0, a2);
      a3 = fmaf(aggP[3][0][cc], w0, a3);
    }
    sPart[0][p][o] = a0; sPart[1][p][o] = a1;
    sPart[2][p][o] = a2; sPart[3][p][o] = a3;
  } else if (tid < 448){
    const int o = tid - 256;
    const int g = o/3, c3 = o - g*3;
    float a0=0.f,a1=0.f,a2=0.f,a3=0.f;
    #pragma unroll 8
    for (int f=0; f<FV; f++){
      float w0 = WmixVl[f*FV+g];
      float w1 = WmixVl[(f+FV)*FV+g];
      a0 = fmaf(aggP[0][0][192+f*3+c3], w0, a0); a0 = fmaf(aggP[0][0][384+f*3+c3], w1, a0);
      a1 = fmaf(aggP[1][0][192+f*3+c3], w0, a1); a1 = fmaf(aggP[1][0][384+f*3+c3], w1, a1);
      a2 = fmaf(aggP[2][0][192+f*3+c3], w0, a2); a2 = fmaf(aggP[2][0][384+f*3+c3], w1, a2);
      a3 = fmaf(aggP[3][0][192+f*3+c3], w0, a3); a3 = fmaf(aggP[3][0][384+f*3+c3], w1, a3);
    }
    vNewL[0][o] = vIb[o*NN + k0]     + a0;
    vNewL[1][o] = vIb[o*NN + k0 + 1] + a1;
    vNewL[2][o] = vIb[o*NN + k0 + 2] + a2;
    vNewL[3][o] = vIb[o*NN + k0 + 3] + a3;
  }
  __syncthreads();

  // ---- E2: s-finalize (tid<128) | out_v (tid 128..319) ----
  if (tid < FS){
    #pragma unroll
    for (int kk=0; kk<4; kk++)
      sNew[kk][tid] = sIb[tid*NN + k0 + kk] + silu_f(sPart[kk][0][tid] + sPart[kk][1][tid]);
  } else if (tid < 320){
    const int o = tid - 128;
    const int g = o/3, c3 = o - g*3;
    float a0 = comL[c3], a1 = comL[c3], a2 = comL[c3], a3 = comL[c3];
    #pragma unroll 8
    for (int f=0; f<FV; f++){
      float wv = WoutV[f*FV+g];
      a0 = fmaf(vNewL[0][f*3+c3], wv, a0);
      a1 = fmaf(vNewL[1][f*3+c3], wv, a1);
      a2 = fmaf(vNewL[2][f*3+c3], wv, a2);
      a3 = fmaf(vNewL[3][f*3+c3], wv, a3);
    }
    outp[(b*NN+k0)*FV*3 + o]   = a0;
    outp[(b*NN+k0+1)*FV*3 + o] = a1;
    outp[(b*NN+k0+2)*FV*3 + o] = a2;
    outp[(b*NN+k0+3)*FV*3 + o] = a3;
  }
  __syncthreads();

  // ---- E3: out_s (tid<128) ----
  if (tid < FS){
    float a0=0.f,a1=0.f,a2=0.f,a3=0.f;
    #pragma unroll 8
    for (int f=0; f<FS; f++){
      float w0 = WoutS[f*FS+tid];
      a0 = fmaf(sNew[0][f], w0, a0);
      a1 = fmaf(sNew[1][f], w0, a1);
      a2 = fmaf(sNew[2][f], w0, a2);
      a3 = fmaf(sNew[3][f], w0, a3);
    }
    outp[BATCH*NN*FV*3 + (b*NN+k0)*FS + tid]   = a0;
    outp[BATCH*NN*FV*3 + (b*NN+k0+1)*FS + tid] = a1;
    outp[BATCH*NN*FV*3 + (b*NN+k0+2)*FS + tid] = a2;
    outp[BATCH*NN*FV*3 + (b*NN+k0+3)*FS + tid] = a3;
  }
}

extern "C" void kernel_launch(void* const* d_in, const int* in_sizes, int n_in,
                              void* d_out, int out_size, void* d_ws, size_t ws_size,
                              hipStream_t stream)
{
  const float* x       = (const float*)d_in[0];
  const float* species = (const float*)d_in[1];
  const float* Wr1     = (const float*)d_in[2];
  const float* Wr2     = (const float*)d_in[3];
  const float* Wsv     = (const float*)d_in[4];
  const float* WmixS   = (const float*)d_in[5];
  const float* WmixV   = (const float*)d_in[6];
  const float* WoutS   = (const float*)d_in[7];
  const float* WoutV   = (const float*)d_in[8];
  float* ws  = (float*)d_ws;
  float* out = (float*)d_out;

  float* sB  = ws + OFF_SB;
  float* vB  = ws + OFF_VB;
  float* t1  = ws + OFF_T1;
  u16*   w2b = (u16*)(ws + OFF_W2B);

  // layer 0 (specialized, 2 receivers/block) -> sB, vB, t1; also Wr2[layer1] -> w2b bf16
  layer0_kernel<<<BATCH*NN/2, 512, 0, stream>>>(x, species, Wr1, Wr2, Wsv,
      WmixS, WmixV, sB, vB, t1, w2b);

  // layer 1 (final, 4 receivers/block): writes d_out directly
  layer_kernel<<<BATCH*NN/4, 512, 0, stream>>>(x, sB, vB, t1,
      Wr1 + NB*HID, w2b, WmixS + 192*FS, WmixV + 128*FV,
      WoutS, WoutV, out);
}